// Round 13
// baseline (1667.077 us; speedup 1.0000x reference)
//
#include <hip/hip_runtime.h>
#include <cstdint>
#include <cstddef>

// Problem constants
#define BB 2
#define SS 4096
#define HH 16
#define DD 64
#define HID 1024
#define NHASH 2
#define CHUNK 64
#define NBUCK 128
#define NCHUNKS 128
#define NSORT 8192
#define BHN 32

// Eigen gebp kc blocking (l1=32KB, f32 AVX2: mr=24,nr=4 -> 288). FROZEN: bucket path.
#define KC_BLOCK 288

// ---------------- workspace layout ----------------
static constexpr size_t SZ_QKV  = (size_t)BB*HH*SS*DD*4;
static constexpr size_t OFF_Q   = 0;
static constexpr size_t OFF_K   = OFF_Q + SZ_QKV;
static constexpr size_t OFF_V   = OFF_K + SZ_QKV;
static constexpr size_t OFF_ROT = OFF_V + SZ_QKV;
static constexpr size_t OFF_QB  = OFF_ROT + (size_t)131072*4;
static constexpr size_t OFF_KB  = OFF_QB + (size_t)BHN*NSORT*4;
static constexpr size_t OFF_SQ  = OFF_KB + (size_t)BHN*NSORT*4;
static constexpr size_t OFF_SK  = OFF_SQ + (size_t)BHN*NSORT*4;
static constexpr size_t OFF_OUTR= OFF_SK + (size_t)BHN*NSORT*4;
static constexpr size_t OFF_LR  = OFF_OUTR + (size_t)BHN*NSORT*DD*4;
static constexpr size_t OFF_HBF = OFF_LR + (size_t)BHN*NSORT*4;      // hid as bf16
static constexpr size_t OFF_WBF = OFF_HBF + (size_t)8192*1024*2;     // w_v as bf16
static constexpr size_t WS_REQUIRED = OFF_WBF + (size_t)1024*1024*2;

// ---------------- XLA f32 helpers (FROZEN: bucket path) ----------------
__device__ __forceinline__ float nofma_mul(float a, float b) {
  float r = a * b;
  asm("" : "+v"(r));
  return r;
}

__device__ __forceinline__ float xla_log1p_f32(float x) {
  float t = nofma_mul(-0.5f, x) + 1.0f;
  float small = nofma_mul(t, x);
  float onep = 1.0f + x;
  float big = (float)log((double)onep);
  return (fabsf(x) < 1e-4f) ? small : big;
}

__device__ __forceinline__ float erfinv_xla_f32(float x) {
  float nxx = -nofma_mul(x, x);
  float w = -xla_log1p_f32(nxx);
  float p;
  if (w < 5.0f) {
    float ww = w - 2.5f;
    p = 2.81022636e-08f;
    p = nofma_mul(p, ww) + 3.43273939e-07f;
    p = nofma_mul(p, ww) + -3.5233877e-06f;
    p = nofma_mul(p, ww) + -4.39150654e-06f;
    p = nofma_mul(p, ww) + 0.00021858087f;
    p = nofma_mul(p, ww) + -0.00125372503f;
    p = nofma_mul(p, ww) + -0.00417768164f;
    p = nofma_mul(p, ww) + 0.246640727f;
    p = nofma_mul(p, ww) + 1.50140941f;
  } else {
    float ww = sqrtf(w) - 3.0f;
    p = -0.000200214257f;
    p = nofma_mul(p, ww) + 0.000100950558f;
    p = nofma_mul(p, ww) + 0.00134934322f;
    p = nofma_mul(p, ww) + -0.00367342844f;
    p = nofma_mul(p, ww) + 0.00573950773f;
    p = nofma_mul(p, ww) + -0.0076224613f;
    p = nofma_mul(p, ww) + 0.00943887047f;
    p = nofma_mul(p, ww) + 1.00167406f;
    p = nofma_mul(p, ww) + 2.83297682f;
  }
  return nofma_mul(p, x);
}

// rotations via threefry2x32 partitionable stream (FROZEN)
__global__ void gen_rot_kernel(float* __restrict__ rot) {
  unsigned i = blockIdx.x * 256 + threadIdx.x;
  if (i >= 131072u) return;
  unsigned x0 = 0u, x1 = i;
  const unsigned ks2 = 0x1BD11BDAu;
#define TF_ROUND(r) { x0 += x1; x1 = (x1 << r) | (x1 >> (32 - r)); x1 ^= x0; }
  TF_ROUND(13) TF_ROUND(15) TF_ROUND(26) TF_ROUND(6)
  /* g=1 */            x1 += ks2 + 1u;
  TF_ROUND(17) TF_ROUND(29) TF_ROUND(16) TF_ROUND(24)
  /* g=2 */ x0 += ks2; x1 += 2u;
  TF_ROUND(13) TF_ROUND(15) TF_ROUND(26) TF_ROUND(6)
  /* g=3 */            x1 += 3u;
  TF_ROUND(17) TF_ROUND(29) TF_ROUND(16) TF_ROUND(24)
  /* g=4 */            x1 += ks2 + 4u;
  TF_ROUND(13) TF_ROUND(15) TF_ROUND(26) TF_ROUND(6)
  /* g=5 */ x0 += ks2; x1 += 5u;
#undef TF_ROUND
  unsigned bits = x0 ^ x1;
  float f = __uint_as_float(0x3f800000u | (bits >> 9)) - 1.0f;
  float u = f * 2.0f - 0.99999994f;
  u = fmaxf(-0.99999994f, u);
  rot[i] = nofma_mul(1.41421356f, erfinv_xla_f32(u));
}

// ---------------- fused Q/K f32 GEMM, Eigen kc=288-blocked ----------------
// Tile 128x64, BK=32, 256 threads, 8x4 micro. Strides: As 133 (133%32=5 ->
// staging-write banks 2-way), Bs 65 (65%32=1 -> all 32 banks, 2-way). Q and
// K fused in one dispatch (shared W): bx<64 -> dec->q, else hid->k.
// Per-output FMA chain strictly ascending k, folds at 288/576/864 (FROZEN).
__global__ __launch_bounds__(256, 4) void gemm_qk_kernel(const float* __restrict__ dec,
                                                         const float* __restrict__ hid,
                                                         float* __restrict__ qd,
                                                         float* __restrict__ kd) {
  __shared__ float As[32][133];
  __shared__ float Bs[32][65];
  int m0 = blockIdx.x * 128;
  const float* A;
  float* dst;
  if (m0 < 8192) { A = dec; dst = qd; }
  else           { A = hid; dst = kd; m0 -= 8192; }
  const int n0 = blockIdx.y * 64;
  const int tid = threadIdx.x;
  const int tr = tid >> 4, tc = tid & 15;
  float accT[8][4], acc[8][4];
#pragma unroll
  for (int i = 0; i < 8; ++i)
#pragma unroll
    for (int j2 = 0; j2 < 4; ++j2) { accT[i][j2] = 0.f; acc[i][j2] = 0.f; }

  const float* wqk = /* W passed via kd? no: */ nullptr;  // placeholder removed below
  (void)wqk;

  // W pointer is passed through a global below (see launcher: we bind it as hid2)
  // -- instead, W is the 5th arg folded into dec/hid scheme; simplest: recompute.
  // (Actual W pointer comes in via the launcher-specialized constant below.)
  extern __constant__ float* __unused_dummy;  // (unused)

  // NOTE: W is provided via the 4th kernel parameter in the launcher version
  // below; this forward declaration style is not used. (Dead code guard.)
  // The real implementation continues in gemm_qk_impl.
}

// Real fused Q/K GEMM (separate function to keep signature clean).
__global__ __launch_bounds__(256, 4) void gemm_qk(const float* __restrict__ dec,
                                                  const float* __restrict__ hid,
                                                  const float* __restrict__ W,
                                                  float* __restrict__ qd,
                                                  float* __restrict__ kd) {
  __shared__ float As[32][133];
  __shared__ float Bs[32][65];
  int m0 = blockIdx.x * 128;
  const float* A;
  float* dst;
  if (m0 < 8192) { A = dec; dst = qd; }
  else           { A = hid; dst = kd; m0 -= 8192; }
  const int n0 = blockIdx.y * 64;
  const int tid = threadIdx.x;
  const int tr = tid >> 4, tc = tid & 15;
  float accT[8][4], acc[8][4];
#pragma unroll
  for (int i = 0; i < 8; ++i)
#pragma unroll
    for (int j2 = 0; j2 < 4; ++j2) { accT[i][j2] = 0.f; acc[i][j2] = 0.f; }

  float4 av[4], bv[2];
#pragma unroll
  for (int it = 0; it < 4; ++it) {
    int id = tid + it * 256;
    av[it] = *(const float4*)(A + (size_t)(m0 + (id >> 3)) * 1024 + ((id & 7) << 2));
  }
#pragma unroll
  for (int it = 0; it < 2; ++it) {
    int id = tid + it * 256;
    bv[it] = *(const float4*)(W + (size_t)(id >> 4) * 1024 + n0 + ((id & 15) << 2));
  }
  for (int kk = 0; kk < 1024; kk += 32) {
#pragma unroll
    for (int it = 0; it < 4; ++it) {
      int id = tid + it * 256;
      int m = id >> 3, kq = (id & 7) << 2;
      As[kq + 0][m] = av[it].x;
      As[kq + 1][m] = av[it].y;
      As[kq + 2][m] = av[it].z;
      As[kq + 3][m] = av[it].w;
    }
#pragma unroll
    for (int it = 0; it < 2; ++it) {
      int id = tid + it * 256;
      *(float4*)&Bs[id >> 4][(id & 15) << 2] = bv[it];
    }
    __syncthreads();
    if (kk + 32 < 1024) {
      int kn = kk + 32;
#pragma unroll
      for (int it = 0; it < 4; ++it) {
        int id = tid + it * 256;
        av[it] = *(const float4*)(A + (size_t)(m0 + (id >> 3)) * 1024 + kn + ((id & 7) << 2));
      }
#pragma unroll
      for (int it = 0; it < 2; ++it) {
        int id = tid + it * 256;
        bv[it] = *(const float4*)(W + (size_t)(kn + (id >> 4)) * 1024 + n0 + ((id & 15) << 2));
      }
    }
#pragma unroll
    for (int k = 0; k < 32; ++k) {   // k strictly ascending: order-exact
      float4 a0 = *(const float4*)&As[k][tr * 8];
      float4 a1 = *(const float4*)&As[k][tr * 8 + 4];
      float4 b0 = *(const float4*)&Bs[k][tc * 4];
      float a[8] = {a0.x, a0.y, a0.z, a0.w, a1.x, a1.y, a1.z, a1.w};
      float b[4] = {b0.x, b0.y, b0.z, b0.w};
#pragma unroll
      for (int i = 0; i < 8; ++i)
#pragma unroll
        for (int j2 = 0; j2 < 4; ++j2)
          acc[i][j2] = fmaf(a[i], b[j2], acc[i][j2]);
    }
    __syncthreads();
    if (((kk + 32) % KC_BLOCK) == 0) {   // folds at 288/576/864
#pragma unroll
      for (int i = 0; i < 8; ++i)
#pragma unroll
        for (int j2 = 0; j2 < 4; ++j2) { accT[i][j2] += acc[i][j2]; acc[i][j2] = 0.f; }
    }
  }
#pragma unroll
  for (int i = 0; i < 8; ++i)
#pragma unroll
    for (int j2 = 0; j2 < 4; ++j2) accT[i][j2] += acc[i][j2];   // tail (160)

  const int h = n0 >> 6;
  const int d = tc << 2;
#pragma unroll
  for (int i = 0; i < 8; ++i) {
    int m = m0 + tr * 8 + i;
    int b = m >> 12, s = m & 4095;
    float4 t = {accT[i][0], accT[i][1], accT[i][2], accT[i][3]};
    *(float4*)(dst + (((size_t)(b * 16 + h) * 4096 + s) << 6) + d) = t;
  }
}

// ---------------- f32 -> bf16 (RNE) cast ----------------
__device__ __forceinline__ unsigned short f2bf(float f) {
  unsigned u = __float_as_uint(f);
  return (unsigned short)((u + 0x7fffu + ((u >> 16) & 1u)) >> 16);
}
__global__ void cast_bf16_kernel(const float* __restrict__ src,
                                 unsigned short* __restrict__ dst, int n4) {
  int i = blockIdx.x * 256 + threadIdx.x;
  if (i >= n4) return;
  float4 v = ((const float4*)src)[i];
  ushort4 o = {f2bf(v.x), f2bf(v.y), f2bf(v.z), f2bf(v.w)};
  ((ushort4*)dst)[i] = o;
}

// ---------------- V GEMM via bf16 MFMA (smooth path; 2% threshold) ---------
typedef __attribute__((ext_vector_type(8))) short bf16x8;
typedef __attribute__((ext_vector_type(4))) float f32x4;

__global__ __launch_bounds__(256) void gemm_v_mfma(const unsigned short* __restrict__ Ab,
                                                   const unsigned short* __restrict__ Wb,
                                                   float* __restrict__ dst) {
  __shared__ unsigned short Bt[64][40];
  const int m0 = blockIdx.x * 64;
  const int n0 = blockIdx.y * 64;
  const int tid = threadIdx.x;
  const int w = tid >> 6, l = tid & 63;
  f32x4 acc[4];
#pragma unroll
  for (int fi = 0; fi < 4; ++fi) acc[fi] = {0.f, 0.f, 0.f, 0.f};

  const int arow = m0 + w * 16 + (l & 15);
  const int kgrp = (l >> 4) * 8;
  for (int kk = 0; kk < 1024; kk += 32) {
    {
      int k = tid >> 3, n8 = (tid & 7) * 8;
      bf16x8 v = *(const bf16x8*)(Wb + (size_t)(kk + k) * 1024 + n0 + n8);
#pragma unroll
      for (int i = 0; i < 8; ++i) Bt[n8 + i][k] = (unsigned short)v[i];
    }
    __syncthreads();
    bf16x8 a = *(const bf16x8*)(Ab + (size_t)arow * 1024 + kk + kgrp);
#pragma unroll
    for (int fi = 0; fi < 4; ++fi) {
      bf16x8 b = *(const bf16x8*)(&Bt[fi * 16 + (l & 15)][kgrp]);
      acc[fi] = __builtin_amdgcn_mfma_f32_16x16x32_bf16(a, b, acc[fi], 0, 0, 0);
    }
    __syncthreads();
  }
  const int h = n0 >> 6;
  const int mrow = m0 + w * 16 + (l >> 4) * 4;
#pragma unroll
  for (int fi = 0; fi < 4; ++fi) {
    int d = fi * 16 + (l & 15);
#pragma unroll
    for (int r = 0; r < 4; ++r) {
      int m = mrow + r;
      int b = m >> 12, s = m & 4095;
      dst[(((size_t)(b * 16 + h) * 4096 + s) << 6) + d] = acc[fi][r];
    }
  }
}

// ---------------- LSH hash (FROZEN numerics) ----------
__global__ __launch_bounds__(128) void hash_kernel(const float* __restrict__ x,
                                                   const float* __restrict__ rot,
                                                   int* __restrict__ buck) {
  __shared__ float rs[8192];
  const int bh = blockIdx.y;
  const int h = bh & 15;
  const int s0 = blockIdx.x * 128;
  const int tid = threadIdx.x;
  for (int off = tid * 4; off < 8192; off += 512)
    *(float4*)&rs[off] = *(const float4*)(rot + (size_t)h * 8192 + off);
  __syncthreads();
  const int s = s0 + tid;
  const float* xr = x + ((size_t)bh * SS + s) * DD;
  float xv[64];
#pragma unroll
  for (int d4 = 0; d4 < 16; ++d4) {
    float4 t = *(const float4*)(xr + d4 * 4);
    xv[d4 * 4] = t.x; xv[d4 * 4 + 1] = t.y; xv[d4 * 4 + 2] = t.z; xv[d4 * 4 + 3] = t.w;
  }
#pragma unroll
  for (int n = 0; n < 2; ++n) {
    float acc[64];
#pragma unroll
    for (int r = 0; r < 64; ++r) acc[r] = 0.f;
#pragma unroll 2
    for (int d4 = 0; d4 < 16; ++d4) {
#pragma unroll
      for (int dd = 0; dd < 4; ++dd) {
        const float xd = xv[d4 * 4 + dd];
        const float* rp = rs + (d4 * 4 + dd) * 128 + n * 64;
#pragma unroll
        for (int r4 = 0; r4 < 16; ++r4) {
          float4 rv = *(const float4*)(rp + r4 * 4);
          acc[r4 * 4 + 0] = fmaf(xd, rv.x, acc[r4 * 4 + 0]);
          acc[r4 * 4 + 1] = fmaf(xd, rv.y, acc[r4 * 4 + 1]);
          acc[r4 * 4 + 2] = fmaf(xd, rv.z, acc[r4 * 4 + 2]);
          acc[r4 * 4 + 3] = fmaf(xd, rv.w, acc[r4 * 4 + 3]);
        }
      }
    }
    float best = -3.402823466e38f;
    int bi = 0;
#pragma unroll
    for (int idx = 0; idx < 128; ++idx) {
      float val = (idx < 64) ? acc[idx] : -acc[idx - 64];
      if (val > best) { best = val; bi = idx; }
    }
    buck[(size_t)bh * NSORT + n * SS + s] = bi + n * NBUCK;
  }
}

// ---------------- parallel stable counting sort ----------------
__global__ __launch_bounds__(256) void sort_kernel(const int* __restrict__ buck,
                                                   int* __restrict__ sorted) {
  const int bh = blockIdx.x >> 1;
  const int half = blockIdx.x & 1;
  const int* bk = buck + (size_t)bh * NSORT + half * SS;
  int* out = sorted + (size_t)bh * NSORT + half * SS;
  __shared__ int cnt[64][128];
  __shared__ int bl[SS];
  __shared__ int bbase[128];
  __shared__ int total[128];
  const int tid = threadIdx.x;
  for (int i = tid; i < 64 * 128; i += 256) (&cnt[0][0])[i] = 0;
  __syncthreads();
#pragma unroll
  for (int j = 0; j < 16; ++j) {
    int i = j * 256 + tid;
    int e = bk[i];
    bl[i] = e;
    atomicAdd(&cnt[i >> 6][e & 127], 1);
  }
  __syncthreads();
  if (tid < 128) {
    int s = 0;
#pragma unroll 4
    for (int c = 0; c < 64; ++c) {
      int t = cnt[c][tid];
      cnt[c][tid] = s;
      s += t;
    }
    total[tid] = s;
  }
  __syncthreads();
  if (tid == 0) {
    int s = 0;
#pragma unroll 4
    for (int v = 0; v < 128; ++v) { bbase[v] = s; s += total[v]; }
  }
  __syncthreads();
  if (tid < 64) {
    const int i0 = tid << 6;
    const int orig0 = half * SS + i0;
#pragma unroll 4
    for (int j = 0; j < 64; ++j) {
      int v = bl[i0 + j] & 127;
      int off = cnt[tid][v];
      cnt[tid][v] = off + 1;
      out[bbase[v] + off] = orig0 + j;
    }
  }
}

// ---------------- fused chunked attention (validated R5≡R6) -------
__global__ __launch_bounds__(256) void attn_kernel(const float* __restrict__ q,
                                                   const float* __restrict__ k,
                                                   const float* __restrict__ v,
                                                   const int* __restrict__ sq,
                                                   const int* __restrict__ sk,
                                                   float* __restrict__ outr,
                                                   float* __restrict__ lr) {
  const int c = blockIdx.x;
  const int bh = blockIdx.y;
  const int cprev = (c + NCHUNKS - 1) & (NCHUNKS - 1);
  __shared__ float Ks[128][68];
  __shared__ float Vs[128][68];
  __shared__ int qpos[64];
  __shared__ int kvpos[128];
  __shared__ int krow[128];
  __shared__ int kdst[64];
  __shared__ float kscale[128];
  const int tid = threadIdx.x;
  const int* sqb = sq + (size_t)bh * NSORT;
  const int* skb = sk + (size_t)bh * NSORT;
  if (tid < 64) {
    int sqc = sqb[c * 64 + tid];
    int sqp = sqb[cprev * 64 + tid];
    qpos[tid] = sqc & (SS - 1);
    kvpos[tid] = sqp & (SS - 1);
    kvpos[64 + tid] = sqc & (SS - 1);
    int skc = skb[c * 64 + tid];
    int skp = skb[cprev * 64 + tid];
    krow[tid] = skp & (SS - 1);
    krow[64 + tid] = skc & (SS - 1);
    kdst[tid] = skc;
  }
  __syncthreads();
  const float* kb = k + (size_t)bh * SS * DD;
  const float* vb = v + (size_t)bh * SS * DD;
#pragma unroll
  for (int it = 0; it < 8; ++it) {
    int id = tid + it * 256;
    int row = id >> 4, c4 = (id & 15) * 4;
    int srow = krow[row];
    *(float4*)&Ks[row][c4] = *(const float4*)(kb + (size_t)srow * DD + c4);
    *(float4*)&Vs[row][c4] = *(const float4*)(vb + (size_t)srow * DD + c4);
  }
  __syncthreads();
  if (tid < 128) {
    float ss = 0.f;
#pragma unroll
    for (int c4 = 0; c4 < 16; ++c4) {
      float4 t = *(const float4*)&Ks[tid][c4 * 4];
      ss += t.x * t.x + t.y * t.y + t.z * t.z + t.w * t.w;
    }
    kscale[tid] = rsqrtf(ss * (1.f / 64.f) + 1e-6f) * 0.125f;
  }
  __syncthreads();

  const int qi = tid >> 2, g = tid & 3;
  const int qp = qpos[qi];
  const float* qrow = q + ((size_t)bh * SS + qp) * DD;
  float qreg[64];
#pragma unroll
  for (int d4 = 0; d4 < 16; ++d4) {
    float4 t = *(const float4*)(qrow + d4 * 4);
    qreg[d4 * 4] = t.x; qreg[d4 * 4 + 1] = t.y; qreg[d4 * 4 + 2] = t.z; qreg[d4 * 4 + 3] = t.w;
  }
  float dots[32];
#pragma unroll
  for (int j = 0; j < 32; ++j) {
    const int kj = j * 4 + g;
    float acc = 0.f;
#pragma unroll
    for (int d4 = 0; d4 < 16; ++d4) {
      float4 t = *(const float4*)&Ks[kj][d4 * 4];
      acc = fmaf(qreg[d4 * 4 + 0], t.x, acc);
      acc = fmaf(qreg[d4 * 4 + 1], t.y, acc);
      acc = fmaf(qreg[d4 * 4 + 2], t.z, acc);
      acc = fmaf(qreg[d4 * 4 + 3], t.w, acc);
    }
    acc *= kscale[kj];
    if (qp == kvpos[kj]) acc = -1e5f;
    dots[j] = acc;
  }
  float m = dots[0];
#pragma unroll
  for (int j = 1; j < 32; ++j) m = fmaxf(m, dots[j]);
  m = fmaxf(m, __shfl_xor(m, 1));
  m = fmaxf(m, __shfl_xor(m, 2));
  float se = 0.f;
#pragma unroll
  for (int j = 0; j < 32; ++j) { dots[j] = expf(dots[j] - m); se += dots[j]; }
  se += __shfl_xor(se, 1);
  se += __shfl_xor(se, 2);
  const float logit = m + logf(se);
  const float seinv = 1.f / se;
  float o[64];
#pragma unroll
  for (int d = 0; d < 64; ++d) o[d] = 0.f;
#pragma unroll
  for (int j = 0; j < 32; ++j) {
    const int kj = j * 4 + g;
    const float p = dots[j] * seinv;
#pragma unroll
    for (int d4 = 0; d4 < 16; ++d4) {
      float4 t = *(const float4*)&Vs[kj][d4 * 4];
      o[d4 * 4 + 0] = fmaf(p, t.x, o[d4 * 4 + 0]);
      o[d4 * 4 + 1] = fmaf(p, t.y, o[d4 * 4 + 1]);
      o[d4 * 4 + 2] = fmaf(p, t.z, o[d4 * 4 + 2]);
      o[d4 * 4 + 3] = fmaf(p, t.w, o[d4 * 4 + 3]);
    }
  }
#pragma unroll
  for (int d = 0; d < 64; ++d) {
    o[d] += __shfl_xor(o[d], 1);
    o[d] += __shfl_xor(o[d], 2);
  }
  const int dest = kdst[qi];
  float* orow = outr + ((size_t)bh * NSORT + dest) * DD;
#pragma unroll
  for (int d4 = 0; d4 < 4; ++d4) {
    float4 t = {o[g * 16 + d4 * 4], o[g * 16 + d4 * 4 + 1], o[g * 16 + d4 * 4 + 2], o[g * 16 + d4 * 4 + 3]};
    *(float4*)(orow + g * 16 + d4 * 4) = t;
  }
  if (g == 0) lr[(size_t)bh * NSORT + dest] = logit;
}

// ---------------- fused merge: round-logsumexp + transpose ------
__global__ void merge_kernel(const float* __restrict__ outr, const float* __restrict__ lr,
                             float* __restrict__ out) {
  const int idx = blockIdx.x * 256 + threadIdx.x;
  const int d4 = idx & 15;
  const int s = (idx >> 4) & (SS - 1);
  const int bh = idx >> 16;
  const int b = bh >> 4, h = bh & 15;
  const float l0 = lr[(size_t)bh * NSORT + s];
  const float l1 = lr[(size_t)bh * NSORT + SS + s];
  const float m = fmaxf(l0, l1);
  float w0 = expf(l0 - m), w1 = expf(l1 - m);
  const float inv = 1.f / (w0 + w1);
  w0 *= inv; w1 *= inv;
  const float4 r0 = *(const float4*)(outr + ((size_t)bh * NSORT + s) * DD + d4 * 4);
  const float4 r1 = *(const float4*)(outr + ((size_t)bh * NSORT + SS + s) * DD + d4 * 4);
  float4 o;
  o.x = w0 * r0.x + w1 * r1.x;
  o.y = w0 * r0.y + w1 * r1.y;
  o.z = w0 * r0.z + w1 * r1.z;
  o.w = w0 * r0.w + w1 * r1.w;
  *(float4*)(out + ((size_t)(b * SS + s) * 1024) + h * 64 + d4 * 4) = o;
}

extern "C" void kernel_launch(void* const* d_in, const int* in_sizes, int n_in,
                              void* d_out, int out_size, void* d_ws, size_t ws_size,
                              hipStream_t stream) {
  if (ws_size < WS_REQUIRED) return;
  const float* dec = (const float*)d_in[0];
  const float* hid = (const float*)d_in[1];
  const float* wqk = (const float*)d_in[2];
  const float* wv  = (const float*)d_in[3];
  float* out = (float*)d_out;
  char* ws = (char*)d_ws;
  float* q    = (float*)(ws + OFF_Q);
  float* kk   = (float*)(ws + OFF_K);
  float* vv   = (float*)(ws + OFF_V);
  float* rotp = (float*)(ws + OFF_ROT);
  int*   qb   = (int*)(ws + OFF_QB);
  int*   kbk  = (int*)(ws + OFF_KB);
  int*   sqi  = (int*)(ws + OFF_SQ);
  int*   ski  = (int*)(ws + OFF_SK);
  float* outr = (float*)(ws + OFF_OUTR);
  float* lrp  = (float*)(ws + OFF_LR);
  unsigned short* hbf = (unsigned short*)(ws + OFF_HBF);
  unsigned short* wbf = (unsigned short*)(ws + OFF_WBF);

  gen_rot_kernel<<<512, 256, 0, stream>>>(rotp);
  cast_bf16_kernel<<<8192, 256, 0, stream>>>(hid, hbf, 8192 * 1024 / 4);
  cast_bf16_kernel<<<1024, 256, 0, stream>>>(wv, wbf, 1024 * 1024 / 4);
  gemm_qk<<<dim3(128, 16), 256, 0, stream>>>(dec, hid, wqk, q, kk);
  gemm_v_mfma<<<dim3(128, 16), 256, 0, stream>>>(hbf, wbf, vv);
  hash_kernel<<<dim3(32, 32), 128, 0, stream>>>(q, rotp, qb);
  hash_kernel<<<dim3(32, 32), 128, 0, stream>>>(kk, rotp, kbk);
  sort_kernel<<<64, 256, 0, stream>>>(qb, sqi);
  sort_kernel<<<64, 256, 0, stream>>>(kbk, ski);
  attn_kernel<<<dim3(128, 32), 256, 0, stream>>>(q, kk, vv, sqi, ski, outr, lrp);
  merge_kernel<<<8192, 256, 0, stream>>>(outr, lrp, out);
}

// Round 14
// 1300.944 us; speedup vs baseline: 1.2814x; 1.2814x over previous
//
#include <hip/hip_runtime.h>
#include <cstdint>
#include <cstddef>

// Problem constants
#define BB 2
#define SS 4096
#define HH 16
#define DD 64
#define HID 1024
#define NHASH 2
#define CHUNK 64
#define NBUCK 128
#define NCHUNKS 128
#define NSORT 8192
#define BHN 32

// Eigen gebp kc blocking (l1=32KB, f32 AVX2: mr=24,nr=4 -> 288). FROZEN: bucket path.
#define KC_BLOCK 288

// ---------------- workspace layout ----------------
static constexpr size_t SZ_QKV  = (size_t)BB*HH*SS*DD*4;
static constexpr size_t OFF_Q   = 0;
static constexpr size_t OFF_K   = OFF_Q + SZ_QKV;
static constexpr size_t OFF_V   = OFF_K + SZ_QKV;
static constexpr size_t OFF_ROT = OFF_V + SZ_QKV;
static constexpr size_t OFF_QB  = OFF_ROT + (size_t)131072*4;
static constexpr size_t OFF_KB  = OFF_QB + (size_t)BHN*NSORT*4;
static constexpr size_t OFF_SQ  = OFF_KB + (size_t)BHN*NSORT*4;
static constexpr size_t OFF_SK  = OFF_SQ + (size_t)BHN*NSORT*4;
static constexpr size_t OFF_OUTR= OFF_SK + (size_t)BHN*NSORT*4;
static constexpr size_t OFF_LR  = OFF_OUTR + (size_t)BHN*NSORT*DD*4;
static constexpr size_t OFF_HBF = OFF_LR + (size_t)BHN*NSORT*4;      // hid as bf16
static constexpr size_t OFF_WBF = OFF_HBF + (size_t)8192*1024*2;     // w_v as bf16
static constexpr size_t WS_REQUIRED = OFF_WBF + (size_t)1024*1024*2;

// ---------------- XLA f32 helpers (FROZEN: bucket path) ----------------
__device__ __forceinline__ float nofma_mul(float a, float b) {
  float r = a * b;
  asm("" : "+v"(r));
  return r;
}

__device__ __forceinline__ float xla_log1p_f32(float x) {
  float t = nofma_mul(-0.5f, x) + 1.0f;
  float small = nofma_mul(t, x);
  float onep = 1.0f + x;
  float big = (float)log((double)onep);
  return (fabsf(x) < 1e-4f) ? small : big;
}

__device__ __forceinline__ float erfinv_xla_f32(float x) {
  float nxx = -nofma_mul(x, x);
  float w = -xla_log1p_f32(nxx);
  float p;
  if (w < 5.0f) {
    float ww = w - 2.5f;
    p = 2.81022636e-08f;
    p = nofma_mul(p, ww) + 3.43273939e-07f;
    p = nofma_mul(p, ww) + -3.5233877e-06f;
    p = nofma_mul(p, ww) + -4.39150654e-06f;
    p = nofma_mul(p, ww) + 0.00021858087f;
    p = nofma_mul(p, ww) + -0.00125372503f;
    p = nofma_mul(p, ww) + -0.00417768164f;
    p = nofma_mul(p, ww) + 0.246640727f;
    p = nofma_mul(p, ww) + 1.50140941f;
  } else {
    float ww = sqrtf(w) - 3.0f;
    p = -0.000200214257f;
    p = nofma_mul(p, ww) + 0.000100950558f;
    p = nofma_mul(p, ww) + 0.00134934322f;
    p = nofma_mul(p, ww) + -0.00367342844f;
    p = nofma_mul(p, ww) + 0.00573950773f;
    p = nofma_mul(p, ww) + -0.0076224613f;
    p = nofma_mul(p, ww) + 0.00943887047f;
    p = nofma_mul(p, ww) + 1.00167406f;
    p = nofma_mul(p, ww) + 2.83297682f;
  }
  return nofma_mul(p, x);
}

// rotations via threefry2x32 partitionable stream (FROZEN)
__global__ void gen_rot_kernel(float* __restrict__ rot) {
  unsigned i = blockIdx.x * 256 + threadIdx.x;
  if (i >= 131072u) return;
  unsigned x0 = 0u, x1 = i;
  const unsigned ks2 = 0x1BD11BDAu;
#define TF_ROUND(r) { x0 += x1; x1 = (x1 << r) | (x1 >> (32 - r)); x1 ^= x0; }
  TF_ROUND(13) TF_ROUND(15) TF_ROUND(26) TF_ROUND(6)
  /* g=1 */            x1 += ks2 + 1u;
  TF_ROUND(17) TF_ROUND(29) TF_ROUND(16) TF_ROUND(24)
  /* g=2 */ x0 += ks2; x1 += 2u;
  TF_ROUND(13) TF_ROUND(15) TF_ROUND(26) TF_ROUND(6)
  /* g=3 */            x1 += 3u;
  TF_ROUND(17) TF_ROUND(29) TF_ROUND(16) TF_ROUND(24)
  /* g=4 */            x1 += ks2 + 4u;
  TF_ROUND(13) TF_ROUND(15) TF_ROUND(26) TF_ROUND(6)
  /* g=5 */ x0 += ks2; x1 += 5u;
#undef TF_ROUND
  unsigned bits = x0 ^ x1;
  float f = __uint_as_float(0x3f800000u | (bits >> 9)) - 1.0f;
  float u = f * 2.0f - 0.99999994f;
  u = fmaxf(-0.99999994f, u);
  rot[i] = nofma_mul(1.41421356f, erfinv_xla_f32(u));
}

// ---------------- fused Q/K f32 GEMM, Eigen kc=288-blocked ----------------
// Tile 128x64, BK=32, 256 threads, 8x4 micro. Strides 133/65 (2-way max on
// staging writes). bx<64 -> dec->q, else hid->k. NO min-waves launch bound
// (R13 lesson: it capped VGPR at 64 -> spills -> 2GB scratch traffic).
// Per-output FMA chain strictly ascending k, folds at 288/576/864 (FROZEN).
__global__ __launch_bounds__(256) void gemm_qk(const float* __restrict__ dec,
                                               const float* __restrict__ hid,
                                               const float* __restrict__ W,
                                               float* __restrict__ qd,
                                               float* __restrict__ kd) {
  __shared__ float As[32][133];
  __shared__ float Bs[32][65];
  int m0 = blockIdx.x * 128;
  const float* A;
  float* dst;
  if (m0 < 8192) { A = dec; dst = qd; }
  else           { A = hid; dst = kd; m0 -= 8192; }
  const int n0 = blockIdx.y * 64;
  const int tid = threadIdx.x;
  const int tr = tid >> 4, tc = tid & 15;
  float accT[8][4], acc[8][4];
#pragma unroll
  for (int i = 0; i < 8; ++i)
#pragma unroll
    for (int j2 = 0; j2 < 4; ++j2) { accT[i][j2] = 0.f; acc[i][j2] = 0.f; }

  float4 av[4], bv[2];
#pragma unroll
  for (int it = 0; it < 4; ++it) {
    int id = tid + it * 256;
    av[it] = *(const float4*)(A + (size_t)(m0 + (id >> 3)) * 1024 + ((id & 7) << 2));
  }
#pragma unroll
  for (int it = 0; it < 2; ++it) {
    int id = tid + it * 256;
    bv[it] = *(const float4*)(W + (size_t)(id >> 4) * 1024 + n0 + ((id & 15) << 2));
  }
  for (int kk = 0; kk < 1024; kk += 32) {
#pragma unroll
    for (int it = 0; it < 4; ++it) {
      int id = tid + it * 256;
      int m = id >> 3, kq = (id & 7) << 2;
      As[kq + 0][m] = av[it].x;
      As[kq + 1][m] = av[it].y;
      As[kq + 2][m] = av[it].z;
      As[kq + 3][m] = av[it].w;
    }
#pragma unroll
    for (int it = 0; it < 2; ++it) {
      int id = tid + it * 256;
      *(float4*)&Bs[id >> 4][(id & 15) << 2] = bv[it];
    }
    __syncthreads();
    if (kk + 32 < 1024) {
      int kn = kk + 32;
#pragma unroll
      for (int it = 0; it < 4; ++it) {
        int id = tid + it * 256;
        av[it] = *(const float4*)(A + (size_t)(m0 + (id >> 3)) * 1024 + kn + ((id & 7) << 2));
      }
#pragma unroll
      for (int it = 0; it < 2; ++it) {
        int id = tid + it * 256;
        bv[it] = *(const float4*)(W + (size_t)(kn + (id >> 4)) * 1024 + n0 + ((id & 15) << 2));
      }
    }
#pragma unroll
    for (int k = 0; k < 32; ++k) {   // k strictly ascending: order-exact
      float4 a0 = *(const float4*)&As[k][tr * 8];
      float4 a1 = *(const float4*)&As[k][tr * 8 + 4];
      float4 b0 = *(const float4*)&Bs[k][tc * 4];
      float a[8] = {a0.x, a0.y, a0.z, a0.w, a1.x, a1.y, a1.z, a1.w};
      float b[4] = {b0.x, b0.y, b0.z, b0.w};
#pragma unroll
      for (int i = 0; i < 8; ++i)
#pragma unroll
        for (int j2 = 0; j2 < 4; ++j2)
          acc[i][j2] = fmaf(a[i], b[j2], acc[i][j2]);
    }
    __syncthreads();
    if (((kk + 32) % KC_BLOCK) == 0) {   // folds at 288/576/864
#pragma unroll
      for (int i = 0; i < 8; ++i)
#pragma unroll
        for (int j2 = 0; j2 < 4; ++j2) { accT[i][j2] += acc[i][j2]; acc[i][j2] = 0.f; }
    }
  }
#pragma unroll
  for (int i = 0; i < 8; ++i)
#pragma unroll
    for (int j2 = 0; j2 < 4; ++j2) accT[i][j2] += acc[i][j2];   // tail (160)

  const int h = n0 >> 6;
  const int d = tc << 2;
#pragma unroll
  for (int i = 0; i < 8; ++i) {
    int m = m0 + tr * 8 + i;
    int b = m >> 12, s = m & 4095;
    float4 t = {accT[i][0], accT[i][1], accT[i][2], accT[i][3]};
    *(float4*)(dst + (((size_t)(b * 16 + h) * 4096 + s) << 6) + d) = t;
  }
}

// ---------------- f32 -> bf16 (RNE) cast ----------------
__device__ __forceinline__ unsigned short f2bf(float f) {
  unsigned u = __float_as_uint(f);
  return (unsigned short)((u + 0x7fffu + ((u >> 16) & 1u)) >> 16);
}
__global__ void cast_bf16_kernel(const float* __restrict__ src,
                                 unsigned short* __restrict__ dst, int n4) {
  int i = blockIdx.x * 256 + threadIdx.x;
  if (i >= n4) return;
  float4 v = ((const float4*)src)[i];
  ushort4 o = {f2bf(v.x), f2bf(v.y), f2bf(v.z), f2bf(v.w)};
  ((ushort4*)dst)[i] = o;
}

// ---------------- V GEMM via bf16 MFMA (smooth path; 2% threshold) ---------
typedef __attribute__((ext_vector_type(8))) short bf16x8;
typedef __attribute__((ext_vector_type(4))) float f32x4;

__global__ __launch_bounds__(256) void gemm_v_mfma(const unsigned short* __restrict__ Ab,
                                                   const unsigned short* __restrict__ Wb,
                                                   float* __restrict__ dst) {
  __shared__ unsigned short Bt[64][40];
  const int m0 = blockIdx.x * 64;
  const int n0 = blockIdx.y * 64;
  const int tid = threadIdx.x;
  const int w = tid >> 6, l = tid & 63;
  f32x4 acc[4];
#pragma unroll
  for (int fi = 0; fi < 4; ++fi) acc[fi] = {0.f, 0.f, 0.f, 0.f};

  const int arow = m0 + w * 16 + (l & 15);
  const int kgrp = (l >> 4) * 8;
  for (int kk = 0; kk < 1024; kk += 32) {
    {
      int k = tid >> 3, n8 = (tid & 7) * 8;
      bf16x8 v = *(const bf16x8*)(Wb + (size_t)(kk + k) * 1024 + n0 + n8);
#pragma unroll
      for (int i = 0; i < 8; ++i) Bt[n8 + i][k] = (unsigned short)v[i];
    }
    __syncthreads();
    bf16x8 a = *(const bf16x8*)(Ab + (size_t)arow * 1024 + kk + kgrp);
#pragma unroll
    for (int fi = 0; fi < 4; ++fi) {
      bf16x8 b = *(const bf16x8*)(&Bt[fi * 16 + (l & 15)][kgrp]);
      acc[fi] = __builtin_amdgcn_mfma_f32_16x16x32_bf16(a, b, acc[fi], 0, 0, 0);
    }
    __syncthreads();
  }
  const int h = n0 >> 6;
  const int mrow = m0 + w * 16 + (l >> 4) * 4;
#pragma unroll
  for (int fi = 0; fi < 4; ++fi) {
    int d = fi * 16 + (l & 15);
#pragma unroll
    for (int r = 0; r < 4; ++r) {
      int m = mrow + r;
      int b = m >> 12, s = m & 4095;
      dst[(((size_t)(b * 16 + h) * 4096 + s) << 6) + d] = acc[fi][r];
    }
  }
}

// ---------------- LSH hash (FROZEN numerics) ----------
__global__ __launch_bounds__(128) void hash_kernel(const float* __restrict__ x,
                                                   const float* __restrict__ rot,
                                                   int* __restrict__ buck) {
  __shared__ float rs[8192];
  const int bh = blockIdx.y;
  const int h = bh & 15;
  const int s0 = blockIdx.x * 128;
  const int tid = threadIdx.x;
  for (int off = tid * 4; off < 8192; off += 512)
    *(float4*)&rs[off] = *(const float4*)(rot + (size_t)h * 8192 + off);
  __syncthreads();
  const int s = s0 + tid;
  const float* xr = x + ((size_t)bh * SS + s) * DD;
  float xv[64];
#pragma unroll
  for (int d4 = 0; d4 < 16; ++d4) {
    float4 t = *(const float4*)(xr + d4 * 4);
    xv[d4 * 4] = t.x; xv[d4 * 4 + 1] = t.y; xv[d4 * 4 + 2] = t.z; xv[d4 * 4 + 3] = t.w;
  }
#pragma unroll
  for (int n = 0; n < 2; ++n) {
    float acc[64];
#pragma unroll
    for (int r = 0; r < 64; ++r) acc[r] = 0.f;
#pragma unroll 2
    for (int d4 = 0; d4 < 16; ++d4) {
#pragma unroll
      for (int dd = 0; dd < 4; ++dd) {
        const float xd = xv[d4 * 4 + dd];
        const float* rp = rs + (d4 * 4 + dd) * 128 + n * 64;
#pragma unroll
        for (int r4 = 0; r4 < 16; ++r4) {
          float4 rv = *(const float4*)(rp + r4 * 4);
          acc[r4 * 4 + 0] = fmaf(xd, rv.x, acc[r4 * 4 + 0]);
          acc[r4 * 4 + 1] = fmaf(xd, rv.y, acc[r4 * 4 + 1]);
          acc[r4 * 4 + 2] = fmaf(xd, rv.z, acc[r4 * 4 + 2]);
          acc[r4 * 4 + 3] = fmaf(xd, rv.w, acc[r4 * 4 + 3]);
        }
      }
    }
    float best = -3.402823466e38f;
    int bi = 0;
#pragma unroll
    for (int idx = 0; idx < 128; ++idx) {
      float val = (idx < 64) ? acc[idx] : -acc[idx - 64];
      if (val > best) { best = val; bi = idx; }
    }
    buck[(size_t)bh * NSORT + n * SS + s] = bi + n * NBUCK;
  }
}

// ---------------- parallel stable counting sort ----------------
__global__ __launch_bounds__(256) void sort_kernel(const int* __restrict__ buck,
                                                   int* __restrict__ sorted) {
  const int bh = blockIdx.x >> 1;
  const int half = blockIdx.x & 1;
  const int* bk = buck + (size_t)bh * NSORT + half * SS;
  int* out = sorted + (size_t)bh * NSORT + half * SS;
  __shared__ int cnt[64][128];
  __shared__ int bl[SS];
  __shared__ int bbase[128];
  __shared__ int total[128];
  const int tid = threadIdx.x;
  for (int i = tid; i < 64 * 128; i += 256) (&cnt[0][0])[i] = 0;
  __syncthreads();
#pragma unroll
  for (int j = 0; j < 16; ++j) {
    int i = j * 256 + tid;
    int e = bk[i];
    bl[i] = e;
    atomicAdd(&cnt[i >> 6][e & 127], 1);
  }
  __syncthreads();
  if (tid < 128) {
    int s = 0;
#pragma unroll 4
    for (int c = 0; c < 64; ++c) {
      int t = cnt[c][tid];
      cnt[c][tid] = s;
      s += t;
    }
    total[tid] = s;
  }
  __syncthreads();
  if (tid == 0) {
    int s = 0;
#pragma unroll 4
    for (int v = 0; v < 128; ++v) { bbase[v] = s; s += total[v]; }
  }
  __syncthreads();
  if (tid < 64) {
    const int i0 = tid << 6;
    const int orig0 = half * SS + i0;
#pragma unroll 4
    for (int j = 0; j < 64; ++j) {
      int v = bl[i0 + j] & 127;
      int off = cnt[tid][v];
      cnt[tid][v] = off + 1;
      out[bbase[v] + off] = orig0 + j;
    }
  }
}

// ---------------- fused chunked attention (validated R5≡R6) -------
__global__ __launch_bounds__(256) void attn_kernel(const float* __restrict__ q,
                                                   const float* __restrict__ k,
                                                   const float* __restrict__ v,
                                                   const int* __restrict__ sq,
                                                   const int* __restrict__ sk,
                                                   float* __restrict__ outr,
                                                   float* __restrict__ lr) {
  const int c = blockIdx.x;
  const int bh = blockIdx.y;
  const int cprev = (c + NCHUNKS - 1) & (NCHUNKS - 1);
  __shared__ float Ks[128][68];
  __shared__ float Vs[128][68];
  __shared__ int qpos[64];
  __shared__ int kvpos[128];
  __shared__ int krow[128];
  __shared__ int kdst[64];
  __shared__ float kscale[128];
  const int tid = threadIdx.x;
  const int* sqb = sq + (size_t)bh * NSORT;
  const int* skb = sk + (size_t)bh * NSORT;
  if (tid < 64) {
    int sqc = sqb[c * 64 + tid];
    int sqp = sqb[cprev * 64 + tid];
    qpos[tid] = sqc & (SS - 1);
    kvpos[tid] = sqp & (SS - 1);
    kvpos[64 + tid] = sqc & (SS - 1);
    int skc = skb[c * 64 + tid];
    int skp = skb[cprev * 64 + tid];
    krow[tid] = skp & (SS - 1);
    krow[64 + tid] = skc & (SS - 1);
    kdst[tid] = skc;
  }
  __syncthreads();
  const float* kb = k + (size_t)bh * SS * DD;
  const float* vb = v + (size_t)bh * SS * DD;
#pragma unroll
  for (int it = 0; it < 8; ++it) {
    int id = tid + it * 256;
    int row = id >> 4, c4 = (id & 15) * 4;
    int srow = krow[row];
    *(float4*)&Ks[row][c4] = *(const float4*)(kb + (size_t)srow * DD + c4);
    *(float4*)&Vs[row][c4] = *(const float4*)(vb + (size_t)srow * DD + c4);
  }
  __syncthreads();
  if (tid < 128) {
    float ss = 0.f;
#pragma unroll
    for (int c4 = 0; c4 < 16; ++c4) {
      float4 t = *(const float4*)&Ks[tid][c4 * 4];
      ss += t.x * t.x + t.y * t.y + t.z * t.z + t.w * t.w;
    }
    kscale[tid] = rsqrtf(ss * (1.f / 64.f) + 1e-6f) * 0.125f;
  }
  __syncthreads();

  const int qi = tid >> 2, g = tid & 3;
  const int qp = qpos[qi];
  const float* qrow = q + ((size_t)bh * SS + qp) * DD;
  float qreg[64];
#pragma unroll
  for (int d4 = 0; d4 < 16; ++d4) {
    float4 t = *(const float4*)(qrow + d4 * 4);
    qreg[d4 * 4] = t.x; qreg[d4 * 4 + 1] = t.y; qreg[d4 * 4 + 2] = t.z; qreg[d4 * 4 + 3] = t.w;
  }
  float dots[32];
#pragma unroll
  for (int j = 0; j < 32; ++j) {
    const int kj = j * 4 + g;
    float acc = 0.f;
#pragma unroll
    for (int d4 = 0; d4 < 16; ++d4) {
      float4 t = *(const float4*)&Ks[kj][d4 * 4];
      acc = fmaf(qreg[d4 * 4 + 0], t.x, acc);
      acc = fmaf(qreg[d4 * 4 + 1], t.y, acc);
      acc = fmaf(qreg[d4 * 4 + 2], t.z, acc);
      acc = fmaf(qreg[d4 * 4 + 3], t.w, acc);
    }
    acc *= kscale[kj];
    if (qp == kvpos[kj]) acc = -1e5f;
    dots[j] = acc;
  }
  float m = dots[0];
#pragma unroll
  for (int j = 1; j < 32; ++j) m = fmaxf(m, dots[j]);
  m = fmaxf(m, __shfl_xor(m, 1));
  m = fmaxf(m, __shfl_xor(m, 2));
  float se = 0.f;
#pragma unroll
  for (int j = 0; j < 32; ++j) { dots[j] = expf(dots[j] - m); se += dots[j]; }
  se += __shfl_xor(se, 1);
  se += __shfl_xor(se, 2);
  const float logit = m + logf(se);
  const float seinv = 1.f / se;
  float o[64];
#pragma unroll
  for (int d = 0; d < 64; ++d) o[d] = 0.f;
#pragma unroll
  for (int j = 0; j < 32; ++j) {
    const int kj = j * 4 + g;
    const float p = dots[j] * seinv;
#pragma unroll
    for (int d4 = 0; d4 < 16; ++d4) {
      float4 t = *(const float4*)&Vs[kj][d4 * 4];
      o[d4 * 4 + 0] = fmaf(p, t.x, o[d4 * 4 + 0]);
      o[d4 * 4 + 1] = fmaf(p, t.y, o[d4 * 4 + 1]);
      o[d4 * 4 + 2] = fmaf(p, t.z, o[d4 * 4 + 2]);
      o[d4 * 4 + 3] = fmaf(p, t.w, o[d4 * 4 + 3]);
    }
  }
#pragma unroll
  for (int d = 0; d < 64; ++d) {
    o[d] += __shfl_xor(o[d], 1);
    o[d] += __shfl_xor(o[d], 2);
  }
  const int dest = kdst[qi];
  float* orow = outr + ((size_t)bh * NSORT + dest) * DD;
#pragma unroll
  for (int d4 = 0; d4 < 4; ++d4) {
    float4 t = {o[g * 16 + d4 * 4], o[g * 16 + d4 * 4 + 1], o[g * 16 + d4 * 4 + 2], o[g * 16 + d4 * 4 + 3]};
    *(float4*)(orow + g * 16 + d4 * 4) = t;
  }
  if (g == 0) lr[(size_t)bh * NSORT + dest] = logit;
}

// ---------------- fused merge: round-logsumexp + transpose ------
__global__ void merge_kernel(const float* __restrict__ outr, const float* __restrict__ lr,
                             float* __restrict__ out) {
  const int idx = blockIdx.x * 256 + threadIdx.x;
  const int d4 = idx & 15;
  const int s = (idx >> 4) & (SS - 1);
  const int bh = idx >> 16;
  const int b = bh >> 4, h = bh & 15;
  const float l0 = lr[(size_t)bh * NSORT + s];
  const float l1 = lr[(size_t)bh * NSORT + SS + s];
  const float m = fmaxf(l0, l1);
  float w0 = expf(l0 - m), w1 = expf(l1 - m);
  const float inv = 1.f / (w0 + w1);
  w0 *= inv; w1 *= inv;
  const float4 r0 = *(const float4*)(outr + ((size_t)bh * NSORT + s) * DD + d4 * 4);
  const float4 r1 = *(const float4*)(outr + ((size_t)bh * NSORT + SS + s) * DD + d4 * 4);
  float4 o;
  o.x = w0 * r0.x + w1 * r1.x;
  o.y = w0 * r0.y + w1 * r1.y;
  o.z = w0 * r0.z + w1 * r1.z;
  o.w = w0 * r0.w + w1 * r1.w;
  *(float4*)(out + ((size_t)(b * SS + s) * 1024) + h * 64 + d4 * 4) = o;
}

extern "C" void kernel_launch(void* const* d_in, const int* in_sizes, int n_in,
                              void* d_out, int out_size, void* d_ws, size_t ws_size,
                              hipStream_t stream) {
  if (ws_size < WS_REQUIRED) return;
  const float* dec = (const float*)d_in[0];
  const float* hid = (const float*)d_in[1];
  const float* wqk = (const float*)d_in[2];
  const float* wv  = (const float*)d_in[3];
  float* out = (float*)d_out;
  char* ws = (char*)d_ws;
  float* q    = (float*)(ws + OFF_Q);
  float* kk   = (float*)(ws + OFF_K);
  float* vv   = (float*)(ws + OFF_V);
  float* rotp = (float*)(ws + OFF_ROT);
  int*   qb   = (int*)(ws + OFF_QB);
  int*   kbk  = (int*)(ws + OFF_KB);
  int*   sqi  = (int*)(ws + OFF_SQ);
  int*   ski  = (int*)(ws + OFF_SK);
  float* outr = (float*)(ws + OFF_OUTR);
  float* lrp  = (float*)(ws + OFF_LR);
  unsigned short* hbf = (unsigned short*)(ws + OFF_HBF);
  unsigned short* wbf = (unsigned short*)(ws + OFF_WBF);

  gen_rot_kernel<<<512, 256, 0, stream>>>(rotp);
  cast_bf16_kernel<<<8192, 256, 0, stream>>>(hid, hbf, 8192 * 1024 / 4);
  cast_bf16_kernel<<<1024, 256, 0, stream>>>(wv, wbf, 1024 * 1024 / 4);
  gemm_qk<<<dim3(128, 16), 256, 0, stream>>>(dec, hid, wqk, q, kk);
  gemm_v_mfma<<<dim3(128, 16), 256, 0, stream>>>(hbf, wbf, vv);
  hash_kernel<<<dim3(32, 32), 128, 0, stream>>>(q, rotp, qb);
  hash_kernel<<<dim3(32, 32), 128, 0, stream>>>(kk, rotp, kbk);
  sort_kernel<<<64, 256, 0, stream>>>(qb, sqi);
  sort_kernel<<<64, 256, 0, stream>>>(kbk, ski);
  attn_kernel<<<dim3(128, 32), 256, 0, stream>>>(q, kk, vv, sqi, ski, outr, lrp);
  merge_kernel<<<8192, 256, 0, stream>>>(outr, lrp, out);
}

// Round 15
// 999.587 us; speedup vs baseline: 1.6678x; 1.3015x over previous
//
#include <hip/hip_runtime.h>
#include <cstdint>
#include <cstddef>

// Problem constants
#define BB 2
#define SS 4096
#define HH 16
#define DD 64
#define HID 1024
#define NHASH 2
#define CHUNK 64
#define NBUCK 128
#define NCHUNKS 128
#define NSORT 8192
#define BHN 32

// Eigen gebp kc blocking (l1=32KB, f32 AVX2: mr=24,nr=4 -> 288). FROZEN: bucket path.
#define KC_BLOCK 288

// ---------------- workspace layout ----------------
static constexpr size_t SZ_QKV  = (size_t)BB*HH*SS*DD*4;
static constexpr size_t OFF_Q   = 0;
static constexpr size_t OFF_K   = OFF_Q + SZ_QKV;
static constexpr size_t OFF_V   = OFF_K + SZ_QKV;
static constexpr size_t OFF_ROT = OFF_V + SZ_QKV;
static constexpr size_t OFF_QB  = OFF_ROT + (size_t)131072*4;        // q-buckets, then undo_k
static constexpr size_t OFF_KB  = OFF_QB + (size_t)BHN*NSORT*4;
static constexpr size_t OFF_SQ  = OFF_KB + (size_t)BHN*NSORT*4;
static constexpr size_t OFF_SK  = OFF_SQ + (size_t)BHN*NSORT*4;
static constexpr size_t OFF_OUTR= OFF_SK + (size_t)BHN*NSORT*4;      // attn out, SORTED rows
static constexpr size_t OFF_LR  = OFF_OUTR + (size_t)BHN*NSORT*DD*4; // logits, SORTED rows
static constexpr size_t OFF_HBF = OFF_LR + (size_t)BHN*NSORT*4;      // hid as bf16
static constexpr size_t OFF_WBF = OFF_HBF + (size_t)8192*1024*2;     // w_v as bf16
static constexpr size_t WS_REQUIRED = OFF_WBF + (size_t)1024*1024*2;

// ---------------- XLA f32 helpers (FROZEN: bucket path) ----------------
__device__ __forceinline__ float nofma_mul(float a, float b) {
  float r = a * b;
  asm("" : "+v"(r));
  return r;
}

__device__ __forceinline__ float xla_log1p_f32(float x) {
  float t = nofma_mul(-0.5f, x) + 1.0f;
  float small = nofma_mul(t, x);
  float onep = 1.0f + x;
  float big = (float)log((double)onep);
  return (fabsf(x) < 1e-4f) ? small : big;
}

__device__ __forceinline__ float erfinv_xla_f32(float x) {
  float nxx = -nofma_mul(x, x);
  float w = -xla_log1p_f32(nxx);
  float p;
  if (w < 5.0f) {
    float ww = w - 2.5f;
    p = 2.81022636e-08f;
    p = nofma_mul(p, ww) + 3.43273939e-07f;
    p = nofma_mul(p, ww) + -3.5233877e-06f;
    p = nofma_mul(p, ww) + -4.39150654e-06f;
    p = nofma_mul(p, ww) + 0.00021858087f;
    p = nofma_mul(p, ww) + -0.00125372503f;
    p = nofma_mul(p, ww) + -0.00417768164f;
    p = nofma_mul(p, ww) + 0.246640727f;
    p = nofma_mul(p, ww) + 1.50140941f;
  } else {
    float ww = sqrtf(w) - 3.0f;
    p = -0.000200214257f;
    p = nofma_mul(p, ww) + 0.000100950558f;
    p = nofma_mul(p, ww) + 0.00134934322f;
    p = nofma_mul(p, ww) + -0.00367342844f;
    p = nofma_mul(p, ww) + 0.00573950773f;
    p = nofma_mul(p, ww) + -0.0076224613f;
    p = nofma_mul(p, ww) + 0.00943887047f;
    p = nofma_mul(p, ww) + 1.00167406f;
    p = nofma_mul(p, ww) + 2.83297682f;
  }
  return nofma_mul(p, x);
}

// rotations via threefry2x32 partitionable stream (FROZEN)
__global__ void gen_rot_kernel(float* __restrict__ rot) {
  unsigned i = blockIdx.x * 256 + threadIdx.x;
  if (i >= 131072u) return;
  unsigned x0 = 0u, x1 = i;
  const unsigned ks2 = 0x1BD11BDAu;
#define TF_ROUND(r) { x0 += x1; x1 = (x1 << r) | (x1 >> (32 - r)); x1 ^= x0; }
  TF_ROUND(13) TF_ROUND(15) TF_ROUND(26) TF_ROUND(6)
  /* g=1 */            x1 += ks2 + 1u;
  TF_ROUND(17) TF_ROUND(29) TF_ROUND(16) TF_ROUND(24)
  /* g=2 */ x0 += ks2; x1 += 2u;
  TF_ROUND(13) TF_ROUND(15) TF_ROUND(26) TF_ROUND(6)
  /* g=3 */            x1 += 3u;
  TF_ROUND(17) TF_ROUND(29) TF_ROUND(16) TF_ROUND(24)
  /* g=4 */            x1 += ks2 + 4u;
  TF_ROUND(13) TF_ROUND(15) TF_ROUND(26) TF_ROUND(6)
  /* g=5 */ x0 += ks2; x1 += 5u;
#undef TF_ROUND
  unsigned bits = x0 ^ x1;
  float f = __uint_as_float(0x3f800000u | (bits >> 9)) - 1.0f;
  float u = f * 2.0f - 0.99999994f;
  u = fmaxf(-0.99999994f, u);
  rot[i] = nofma_mul(1.41421356f, erfinv_xla_f32(u));
}

// ---------------- f32 GEMM (Q,K), Eigen kc=288-blocked (R12 EXACT) --------
// 128x64 tile, BK=32, 256 threads, 8x4 micro, strides 132/68, VGPR ~116.
// Measured 282us/dispatch. Per-output FMA chain strictly ascending k, folds
// at 288/576/864 -> buckets bit-identical. DO NOT add min-waves bound (R13)
// or odd-dword pads (R14).
__global__ __launch_bounds__(256) void gemm_kernel(const float* __restrict__ A,
                                                   const float* __restrict__ W,
                                                   float* __restrict__ dst) {
  __shared__ float As[32][132];
  __shared__ float Bs[32][68];
  const int m0 = blockIdx.x * 128;
  const int n0 = blockIdx.y * 64;
  const int tid = threadIdx.x;
  const int tr = tid >> 4, tc = tid & 15;
  float accT[8][4], acc[8][4];
#pragma unroll
  for (int i = 0; i < 8; ++i)
#pragma unroll
    for (int j2 = 0; j2 < 4; ++j2) { accT[i][j2] = 0.f; acc[i][j2] = 0.f; }

  float4 av[4], bv[2];
#pragma unroll
  for (int it = 0; it < 4; ++it) {
    int id = tid + it * 256;
    av[it] = *(const float4*)(A + (size_t)(m0 + (id >> 3)) * 1024 + ((id & 7) << 2));
  }
#pragma unroll
  for (int it = 0; it < 2; ++it) {
    int id = tid + it * 256;
    bv[it] = *(const float4*)(W + (size_t)(id >> 4) * 1024 + n0 + ((id & 15) << 2));
  }
  for (int kk = 0; kk < 1024; kk += 32) {
#pragma unroll
    for (int it = 0; it < 4; ++it) {
      int id = tid + it * 256;
      int m = id >> 3, kq = (id & 7) << 2;
      As[kq + 0][m] = av[it].x;
      As[kq + 1][m] = av[it].y;
      As[kq + 2][m] = av[it].z;
      As[kq + 3][m] = av[it].w;
    }
#pragma unroll
    for (int it = 0; it < 2; ++it) {
      int id = tid + it * 256;
      *(float4*)&Bs[id >> 4][(id & 15) << 2] = bv[it];
    }
    __syncthreads();
    if (kk + 32 < 1024) {
      int kn = kk + 32;
#pragma unroll
      for (int it = 0; it < 4; ++it) {
        int id = tid + it * 256;
        av[it] = *(const float4*)(A + (size_t)(m0 + (id >> 3)) * 1024 + kn + ((id & 7) << 2));
      }
#pragma unroll
      for (int it = 0; it < 2; ++it) {
        int id = tid + it * 256;
        bv[it] = *(const float4*)(W + (size_t)(kn + (id >> 4)) * 1024 + n0 + ((id & 15) << 2));
      }
    }
#pragma unroll
    for (int k = 0; k < 32; ++k) {
      float4 a0 = *(const float4*)&As[k][tr * 8];
      float4 a1 = *(const float4*)&As[k][tr * 8 + 4];
      float4 b0 = *(const float4*)&Bs[k][tc * 4];
      float a[8] = {a0.x, a0.y, a0.z, a0.w, a1.x, a1.y, a1.z, a1.w};
      float b[4] = {b0.x, b0.y, b0.z, b0.w};
#pragma unroll
      for (int i = 0; i < 8; ++i)
#pragma unroll
        for (int j2 = 0; j2 < 4; ++j2)
          acc[i][j2] = fmaf(a[i], b[j2], acc[i][j2]);
    }
    __syncthreads();
    if (((kk + 32) % KC_BLOCK) == 0) {
#pragma unroll
      for (int i = 0; i < 8; ++i)
#pragma unroll
        for (int j2 = 0; j2 < 4; ++j2) { accT[i][j2] += acc[i][j2]; acc[i][j2] = 0.f; }
    }
  }
#pragma unroll
  for (int i = 0; i < 8; ++i)
#pragma unroll
    for (int j2 = 0; j2 < 4; ++j2) accT[i][j2] += acc[i][j2];

  const int h = n0 >> 6;
  const int d = tc << 2;
#pragma unroll
  for (int i = 0; i < 8; ++i) {
    int m = m0 + tr * 8 + i;
    int b = m >> 12, s = m & 4095;
    float4 t = {accT[i][0], accT[i][1], accT[i][2], accT[i][3]};
    *(float4*)(dst + (((size_t)(b * 16 + h) * 4096 + s) << 6) + d) = t;
  }
}

// ---------------- f32 -> bf16 (RNE) cast ----------------
__device__ __forceinline__ unsigned short f2bf(float f) {
  unsigned u = __float_as_uint(f);
  return (unsigned short)((u + 0x7fffu + ((u >> 16) & 1u)) >> 16);
}
__global__ void cast_bf16_kernel(const float* __restrict__ src,
                                 unsigned short* __restrict__ dst, int n4) {
  int i = blockIdx.x * 256 + threadIdx.x;
  if (i >= n4) return;
  float4 v = ((const float4*)src)[i];
  ushort4 o = {f2bf(v.x), f2bf(v.y), f2bf(v.z), f2bf(v.w)};
  ((ushort4*)dst)[i] = o;
}

// ---------------- V GEMM via bf16 MFMA (smooth path; 2% threshold) ---------
typedef __attribute__((ext_vector_type(8))) short bf16x8;
typedef __attribute__((ext_vector_type(4))) float f32x4;

__global__ __launch_bounds__(256) void gemm_v_mfma(const unsigned short* __restrict__ Ab,
                                                   const unsigned short* __restrict__ Wb,
                                                   float* __restrict__ dst) {
  __shared__ unsigned short Bt[64][40];
  const int m0 = blockIdx.x * 64;
  const int n0 = blockIdx.y * 64;
  const int tid = threadIdx.x;
  const int w = tid >> 6, l = tid & 63;
  f32x4 acc[4];
#pragma unroll
  for (int fi = 0; fi < 4; ++fi) acc[fi] = {0.f, 0.f, 0.f, 0.f};

  const int arow = m0 + w * 16 + (l & 15);
  const int kgrp = (l >> 4) * 8;
  for (int kk = 0; kk < 1024; kk += 32) {
    {
      int k = tid >> 3, n8 = (tid & 7) * 8;
      bf16x8 v = *(const bf16x8*)(Wb + (size_t)(kk + k) * 1024 + n0 + n8);
#pragma unroll
      for (int i = 0; i < 8; ++i) Bt[n8 + i][k] = (unsigned short)v[i];
    }
    __syncthreads();
    bf16x8 a = *(const bf16x8*)(Ab + (size_t)arow * 1024 + kk + kgrp);
#pragma unroll
    for (int fi = 0; fi < 4; ++fi) {
      bf16x8 b = *(const bf16x8*)(&Bt[fi * 16 + (l & 15)][kgrp]);
      acc[fi] = __builtin_amdgcn_mfma_f32_16x16x32_bf16(a, b, acc[fi], 0, 0, 0);
    }
    __syncthreads();
  }
  const int h = n0 >> 6;
  const int mrow = m0 + w * 16 + (l >> 4) * 4;
#pragma unroll
  for (int fi = 0; fi < 4; ++fi) {
    int d = fi * 16 + (l & 15);
#pragma unroll
    for (int r = 0; r < 4; ++r) {
      int m = mrow + r;
      int b = m >> 12, s = m & 4095;
      dst[(((size_t)(b * 16 + h) * 4096 + s) << 6) + d] = acc[fi][r];
    }
  }
}

// ---------------- LSH hash (FROZEN numerics) ----------
__global__ __launch_bounds__(128) void hash_kernel(const float* __restrict__ x,
                                                   const float* __restrict__ rot,
                                                   int* __restrict__ buck) {
  __shared__ float rs[8192];
  const int bh = blockIdx.y;
  const int h = bh & 15;
  const int s0 = blockIdx.x * 128;
  const int tid = threadIdx.x;
  for (int off = tid * 4; off < 8192; off += 512)
    *(float4*)&rs[off] = *(const float4*)(rot + (size_t)h * 8192 + off);
  __syncthreads();
  const int s = s0 + tid;
  const float* xr = x + ((size_t)bh * SS + s) * DD;
  float xv[64];
#pragma unroll
  for (int d4 = 0; d4 < 16; ++d4) {
    float4 t = *(const float4*)(xr + d4 * 4);
    xv[d4 * 4] = t.x; xv[d4 * 4 + 1] = t.y; xv[d4 * 4 + 2] = t.z; xv[d4 * 4 + 3] = t.w;
  }
#pragma unroll
  for (int n = 0; n < 2; ++n) {
    float acc[64];
#pragma unroll
    for (int r = 0; r < 64; ++r) acc[r] = 0.f;
#pragma unroll 2
    for (int d4 = 0; d4 < 16; ++d4) {
#pragma unroll
      for (int dd = 0; dd < 4; ++dd) {
        const float xd = xv[d4 * 4 + dd];
        const float* rp = rs + (d4 * 4 + dd) * 128 + n * 64;
#pragma unroll
        for (int r4 = 0; r4 < 16; ++r4) {
          float4 rv = *(const float4*)(rp + r4 * 4);
          acc[r4 * 4 + 0] = fmaf(xd, rv.x, acc[r4 * 4 + 0]);
          acc[r4 * 4 + 1] = fmaf(xd, rv.y, acc[r4 * 4 + 1]);
          acc[r4 * 4 + 2] = fmaf(xd, rv.z, acc[r4 * 4 + 2]);
          acc[r4 * 4 + 3] = fmaf(xd, rv.w, acc[r4 * 4 + 3]);
        }
      }
    }
    float best = -3.402823466e38f;
    int bi = 0;
#pragma unroll
    for (int idx = 0; idx < 128; ++idx) {
      float val = (idx < 64) ? acc[idx] : -acc[idx - 64];
      if (val > best) { best = val; bi = idx; }
    }
    buck[(size_t)bh * NSORT + n * SS + s] = bi + n * NBUCK;
  }
}

// ---------------- parallel stable counting sort ----------------
__global__ __launch_bounds__(256) void sort_kernel(const int* __restrict__ buck,
                                                   int* __restrict__ sorted) {
  const int bh = blockIdx.x >> 1;
  const int half = blockIdx.x & 1;
  const int* bk = buck + (size_t)bh * NSORT + half * SS;
  int* out = sorted + (size_t)bh * NSORT + half * SS;
  __shared__ int cnt[64][128];
  __shared__ int bl[SS];
  __shared__ int bbase[128];
  __shared__ int total[128];
  const int tid = threadIdx.x;
  for (int i = tid; i < 64 * 128; i += 256) (&cnt[0][0])[i] = 0;
  __syncthreads();
#pragma unroll
  for (int j = 0; j < 16; ++j) {
    int i = j * 256 + tid;
    int e = bk[i];
    bl[i] = e;
    atomicAdd(&cnt[i >> 6][e & 127], 1);
  }
  __syncthreads();
  if (tid < 128) {
    int s = 0;
#pragma unroll 4
    for (int c = 0; c < 64; ++c) {
      int t = cnt[c][tid];
      cnt[c][tid] = s;
      s += t;
    }
    total[tid] = s;
  }
  __syncthreads();
  if (tid == 0) {
    int s = 0;
#pragma unroll 4
    for (int v = 0; v < 128; ++v) { bbase[v] = s; s += total[v]; }
  }
  __syncthreads();
  if (tid < 64) {
    const int i0 = tid << 6;
    const int orig0 = half * SS + i0;
#pragma unroll 4
    for (int j = 0; j < 64; ++j) {
      int v = bl[i0 + j] & 127;
      int off = cnt[tid][v];
      cnt[tid][v] = off + 1;
      out[bbase[v] + off] = orig0 + j;
    }
  }
}

// ---------------- undo indices: undo[srt[j]] = j ----------------
__global__ void undo_kernel(const int* __restrict__ srt, int* __restrict__ undo) {
  const int bh = blockIdx.x;
  for (int j = threadIdx.x; j < NSORT; j += 256)
    undo[(size_t)bh * NSORT + srt[(size_t)bh * NSORT + j]] = j;
}

// ---------------- fused chunked attention, SORTED-ORDER writes -------
// Writes out/logit at row j = c*64+qi (coalesced); merge applies the undo
// permutation (R6-validated semantics).
__global__ __launch_bounds__(256) void attn_kernel(const float* __restrict__ q,
                                                   const float* __restrict__ k,
                                                   const float* __restrict__ v,
                                                   const int* __restrict__ sq,
                                                   const int* __restrict__ sk,
                                                   float* __restrict__ outr,
                                                   float* __restrict__ lr) {
  const int c = blockIdx.x;
  const int bh = blockIdx.y;
  const int cprev = (c + NCHUNKS - 1) & (NCHUNKS - 1);
  __shared__ float Ks[128][68];
  __shared__ float Vs[128][68];
  __shared__ int qpos[64];
  __shared__ int kvpos[128];
  __shared__ int krow[128];
  __shared__ float kscale[128];
  const int tid = threadIdx.x;
  const int* sqb = sq + (size_t)bh * NSORT;
  const int* skb = sk + (size_t)bh * NSORT;
  if (tid < 64) {
    int sqc = sqb[c * 64 + tid];
    int sqp = sqb[cprev * 64 + tid];
    qpos[tid] = sqc & (SS - 1);
    kvpos[tid] = sqp & (SS - 1);
    kvpos[64 + tid] = sqc & (SS - 1);
    int skc = skb[c * 64 + tid];
    int skp = skb[cprev * 64 + tid];
    krow[tid] = skp & (SS - 1);
    krow[64 + tid] = skc & (SS - 1);
  }
  __syncthreads();
  const float* kb = k + (size_t)bh * SS * DD;
  const float* vb = v + (size_t)bh * SS * DD;
#pragma unroll
  for (int it = 0; it < 8; ++it) {
    int id = tid + it * 256;
    int row = id >> 4, c4 = (id & 15) * 4;
    int srow = krow[row];
    *(float4*)&Ks[row][c4] = *(const float4*)(kb + (size_t)srow * DD + c4);
    *(float4*)&Vs[row][c4] = *(const float4*)(vb + (size_t)srow * DD + c4);
  }
  __syncthreads();
  if (tid < 128) {
    float ss = 0.f;
#pragma unroll
    for (int c4 = 0; c4 < 16; ++c4) {
      float4 t = *(const float4*)&Ks[tid][c4 * 4];
      ss += t.x * t.x + t.y * t.y + t.z * t.z + t.w * t.w;
    }
    kscale[tid] = rsqrtf(ss * (1.f / 64.f) + 1e-6f) * 0.125f;
  }
  __syncthreads();

  const int qi = tid >> 2, g = tid & 3;
  const int qp = qpos[qi];
  const float* qrow = q + ((size_t)bh * SS + qp) * DD;
  float qreg[64];
#pragma unroll
  for (int d4 = 0; d4 < 16; ++d4) {
    float4 t = *(const float4*)(qrow + d4 * 4);
    qreg[d4 * 4] = t.x; qreg[d4 * 4 + 1] = t.y; qreg[d4 * 4 + 2] = t.z; qreg[d4 * 4 + 3] = t.w;
  }
  float dots[32];
#pragma unroll
  for (int j = 0; j < 32; ++j) {
    const int kj = j * 4 + g;
    float acc = 0.f;
#pragma unroll
    for (int d4 = 0; d4 < 16; ++d4) {
      float4 t = *(const float4*)&Ks[kj][d4 * 4];
      acc = fmaf(qreg[d4 * 4 + 0], t.x, acc);
      acc = fmaf(qreg[d4 * 4 + 1], t.y, acc);
      acc = fmaf(qreg[d4 * 4 + 2], t.z, acc);
      acc = fmaf(qreg[d4 * 4 + 3], t.w, acc);
    }
    acc *= kscale[kj];
    if (qp == kvpos[kj]) acc = -1e5f;
    dots[j] = acc;
  }
  float m = dots[0];
#pragma unroll
  for (int j = 1; j < 32; ++j) m = fmaxf(m, dots[j]);
  m = fmaxf(m, __shfl_xor(m, 1));
  m = fmaxf(m, __shfl_xor(m, 2));
  float se = 0.f;
#pragma unroll
  for (int j = 0; j < 32; ++j) { dots[j] = expf(dots[j] - m); se += dots[j]; }
  se += __shfl_xor(se, 1);
  se += __shfl_xor(se, 2);
  const float logit = m + logf(se);
  const float seinv = 1.f / se;
  float o[64];
#pragma unroll
  for (int d = 0; d < 64; ++d) o[d] = 0.f;
#pragma unroll
  for (int j = 0; j < 32; ++j) {
    const int kj = j * 4 + g;
    const float p = dots[j] * seinv;
#pragma unroll
    for (int d4 = 0; d4 < 16; ++d4) {
      float4 t = *(const float4*)&Vs[kj][d4 * 4];
      o[d4 * 4 + 0] = fmaf(p, t.x, o[d4 * 4 + 0]);
      o[d4 * 4 + 1] = fmaf(p, t.y, o[d4 * 4 + 1]);
      o[d4 * 4 + 2] = fmaf(p, t.z, o[d4 * 4 + 2]);
      o[d4 * 4 + 3] = fmaf(p, t.w, o[d4 * 4 + 3]);
    }
  }
#pragma unroll
  for (int d = 0; d < 64; ++d) {
    o[d] += __shfl_xor(o[d], 1);
    o[d] += __shfl_xor(o[d], 2);
  }
  // coalesced write at sorted row j = c*64 + qi
  float* orow = outr + ((size_t)bh * NSORT + c * 64 + qi) * DD;
#pragma unroll
  for (int d4 = 0; d4 < 4; ++d4) {
    float4 t = {o[g * 16 + d4 * 4], o[g * 16 + d4 * 4 + 1], o[g * 16 + d4 * 4 + 2], o[g * 16 + d4 * 4 + 3]};
    *(float4*)(orow + g * 16 + d4 * 4) = t;
  }
  if (g == 0) lr[(size_t)bh * NSORT + c * 64 + qi] = logit;
}

// ---------------- merge: undo-gather + round-logsumexp + transpose ------
__global__ void merge_kernel(const float* __restrict__ outr, const float* __restrict__ lr,
                             const int* __restrict__ undo, float* __restrict__ out) {
  const int idx = blockIdx.x * 256 + threadIdx.x;   // over B*H*S*16
  const int d4 = idx & 15;
  const int s = (idx >> 4) & (SS - 1);
  const int bh = idx >> 16;
  const int b = bh >> 4, h = bh & 15;
  const int u0 = undo[(size_t)bh * NSORT + s];
  const int u1 = undo[(size_t)bh * NSORT + SS + s];
  const float l0 = lr[(size_t)bh * NSORT + u0];
  const float l1 = lr[(size_t)bh * NSORT + u1];
  const float m = fmaxf(l0, l1);
  float w0 = expf(l0 - m), w1 = expf(l1 - m);
  const float inv = 1.f / (w0 + w1);
  w0 *= inv; w1 *= inv;
  const float4 r0 = *(const float4*)(outr + ((size_t)bh * NSORT + u0) * DD + d4 * 4);
  const float4 r1 = *(const float4*)(outr + ((size_t)bh * NSORT + u1) * DD + d4 * 4);
  float4 o;
  o.x = w0 * r0.x + w1 * r1.x;
  o.y = w0 * r0.y + w1 * r1.y;
  o.z = w0 * r0.z + w1 * r1.z;
  o.w = w0 * r0.w + w1 * r1.w;
  *(float4*)(out + ((size_t)(b * SS + s) * 1024) + h * 64 + d4 * 4) = o;
}

extern "C" void kernel_launch(void* const* d_in, const int* in_sizes, int n_in,
                              void* d_out, int out_size, void* d_ws, size_t ws_size,
                              hipStream_t stream) {
  if (ws_size < WS_REQUIRED) return;
  const float* dec = (const float*)d_in[0];
  const float* hid = (const float*)d_in[1];
  const float* wqk = (const float*)d_in[2];
  const float* wv  = (const float*)d_in[3];
  float* out = (float*)d_out;
  char* ws = (char*)d_ws;
  float* q    = (float*)(ws + OFF_Q);
  float* kk   = (float*)(ws + OFF_K);
  float* vv   = (float*)(ws + OFF_V);
  float* rotp = (float*)(ws + OFF_ROT);
  int*   qb   = (int*)(ws + OFF_QB);    // q-buckets, then undo_k
  int*   kbk  = (int*)(ws + OFF_KB);
  int*   sqi  = (int*)(ws + OFF_SQ);
  int*   ski  = (int*)(ws + OFF_SK);
  float* outr = (float*)(ws + OFF_OUTR);
  float* lrp  = (float*)(ws + OFF_LR);
  unsigned short* hbf = (unsigned short*)(ws + OFF_HBF);
  unsigned short* wbf = (unsigned short*)(ws + OFF_WBF);

  gen_rot_kernel<<<512, 256, 0, stream>>>(rotp);
  cast_bf16_kernel<<<8192, 256, 0, stream>>>(hid, hbf, 8192 * 1024 / 4);
  cast_bf16_kernel<<<1024, 256, 0, stream>>>(wv, wbf, 1024 * 1024 / 4);
  gemm_kernel<<<dim3(64, 16), 256, 0, stream>>>(dec, wqk, q);
  gemm_kernel<<<dim3(64, 16), 256, 0, stream>>>(hid, wqk, kk);
  gemm_v_mfma<<<dim3(128, 16), 256, 0, stream>>>(hbf, wbf, vv);
  hash_kernel<<<dim3(32, 32), 128, 0, stream>>>(q, rotp, qb);
  hash_kernel<<<dim3(32, 32), 128, 0, stream>>>(kk, rotp, kbk);
  sort_kernel<<<64, 256, 0, stream>>>(qb, sqi);
  sort_kernel<<<64, 256, 0, stream>>>(kbk, ski);
  undo_kernel<<<32, 256, 0, stream>>>(ski, qb);   // qb now holds undo_k
  attn_kernel<<<dim3(128, 32), 256, 0, stream>>>(q, kk, vv, sqi, ski, outr, lrp);
  merge_kernel<<<8192, 256, 0, stream>>>(outr, lrp, qb, out);
}

// Round 17
// 826.515 us; speedup vs baseline: 2.0170x; 1.2094x over previous
//
#include <hip/hip_runtime.h>
#include <cstdint>
#include <cstddef>

// Problem constants
#define BB 2
#define SS 4096
#define HH 16
#define DD 64
#define HID 1024
#define NHASH 2
#define CHUNK 64
#define NBUCK 128
#define NCHUNKS 128
#define NSORT 8192
#define BHN 32

// Eigen gebp kc blocking (l1=32KB, f32 AVX2: mr=24,nr=4 -> 288). FROZEN: bucket path.
#define KC_BLOCK 288

// ---------------- workspace layout ----------------
static constexpr size_t SZ_QKV  = (size_t)BB*HH*SS*DD*4;             // 32 MB
static constexpr size_t OFF_Q   = 0;
static constexpr size_t OFF_K   = OFF_Q + SZ_QKV;
static constexpr size_t OFF_V   = OFF_K + SZ_QKV;                    // reused: V bf16 (16MB)
static constexpr size_t OFF_ROT = OFF_V + SZ_QKV;
static constexpr size_t OFF_QB  = OFF_ROT + (size_t)131072*4;        // q-buckets, then undo_k
static constexpr size_t OFF_KB  = OFF_QB + (size_t)BHN*NSORT*4;
static constexpr size_t OFF_SQ  = OFF_KB + (size_t)BHN*NSORT*4;
static constexpr size_t OFF_SK  = OFF_SQ + (size_t)BHN*NSORT*4;
static constexpr size_t OFF_OUTR= OFF_SK + (size_t)BHN*NSORT*4;      // attn out, SORTED rows
static constexpr size_t OFF_LR  = OFF_OUTR + (size_t)BHN*NSORT*DD*4; // logits, SORTED rows
static constexpr size_t OFF_HBF = OFF_LR + (size_t)BHN*NSORT*4;      // hid as bf16 (16MB)
static constexpr size_t OFF_WBF = OFF_HBF + (size_t)8192*1024*2;     // w_v as bf16 (2MB)
static constexpr size_t OFF_QBF = OFF_WBF + (size_t)1024*1024*2;     // q as bf16 (16MB)
static constexpr size_t OFF_KBF = OFF_QBF + (size_t)BHN*SS*DD*2;     // k as bf16 (16MB)
static constexpr size_t WS_REQUIRED = OFF_KBF + (size_t)BHN*SS*DD*2; // ~216MB (<229.5 proven)

// ---------------- XLA f32 helpers (FROZEN: bucket path) ----------------
__device__ __forceinline__ float nofma_mul(float a, float b) {
  float r = a * b;
  asm("" : "+v"(r));
  return r;
}

__device__ __forceinline__ float xla_log1p_f32(float x) {
  float t = nofma_mul(-0.5f, x) + 1.0f;
  float small = nofma_mul(t, x);
  float onep = 1.0f + x;
  float big = (float)log((double)onep);
  return (fabsf(x) < 1e-4f) ? small : big;
}

__device__ __forceinline__ float erfinv_xla_f32(float x) {
  float nxx = -nofma_mul(x, x);
  float w = -xla_log1p_f32(nxx);
  float p;
  if (w < 5.0f) {
    float ww = w - 2.5f;
    p = 2.81022636e-08f;
    p = nofma_mul(p, ww) + 3.43273939e-07f;
    p = nofma_mul(p, ww) + -3.5233877e-06f;
    p = nofma_mul(p, ww) + -4.39150654e-06f;
    p = nofma_mul(p, ww) + 0.00021858087f;
    p = nofma_mul(p, ww) + -0.00125372503f;
    p = nofma_mul(p, ww) + -0.00417768164f;
    p = nofma_mul(p, ww) + 0.246640727f;
    p = nofma_mul(p, ww) + 1.50140941f;
  } else {
    float ww = sqrtf(w) - 3.0f;
    p = -0.000200214257f;
    p = nofma_mul(p, ww) + 0.000100950558f;
    p = nofma_mul(p, ww) + 0.00134934322f;
    p = nofma_mul(p, ww) + -0.00367342844f;
    p = nofma_mul(p, ww) + 0.00573950773f;
    p = nofma_mul(p, ww) + -0.0076224613f;
    p = nofma_mul(p, ww) + 0.00943887047f;
    p = nofma_mul(p, ww) + 1.00167406f;
    p = nofma_mul(p, ww) + 2.83297682f;
  }
  return nofma_mul(p, x);
}

// rotations via threefry2x32 partitionable stream (FROZEN)
__global__ void gen_rot_kernel(float* __restrict__ rot) {
  unsigned i = blockIdx.x * 256 + threadIdx.x;
  if (i >= 131072u) return;
  unsigned x0 = 0u, x1 = i;
  const unsigned ks2 = 0x1BD11BDAu;
#define TF_ROUND(r) { x0 += x1; x1 = (x1 << r) | (x1 >> (32 - r)); x1 ^= x0; }
  TF_ROUND(13) TF_ROUND(15) TF_ROUND(26) TF_ROUND(6)
  /* g=1 */            x1 += ks2 + 1u;
  TF_ROUND(17) TF_ROUND(29) TF_ROUND(16) TF_ROUND(24)
  /* g=2 */ x0 += ks2; x1 += 2u;
  TF_ROUND(13) TF_ROUND(15) TF_ROUND(26) TF_ROUND(6)
  /* g=3 */            x1 += 3u;
  TF_ROUND(17) TF_ROUND(29) TF_ROUND(16) TF_ROUND(24)
  /* g=4 */            x1 += ks2 + 4u;
  TF_ROUND(13) TF_ROUND(15) TF_ROUND(26) TF_ROUND(6)
  /* g=5 */ x0 += ks2; x1 += 5u;
#undef TF_ROUND
  unsigned bits = x0 ^ x1;
  float f = __uint_as_float(0x3f800000u | (bits >> 9)) - 1.0f;
  float u = f * 2.0f - 0.99999994f;
  u = fmaxf(-0.99999994f, u);
  rot[i] = nofma_mul(1.41421356f, erfinv_xla_f32(u));
}

// ---------------- f32 GEMM (Q,K), Eigen kc=288-blocked (R12 EXACT) --------
__global__ __launch_bounds__(256) void gemm_kernel(const float* __restrict__ A,
                                                   const float* __restrict__ W,
                                                   float* __restrict__ dst) {
  __shared__ float As[32][132];
  __shared__ float Bs[32][68];
  const int m0 = blockIdx.x * 128;
  const int n0 = blockIdx.y * 64;
  const int tid = threadIdx.x;
  const int tr = tid >> 4, tc = tid & 15;
  float accT[8][4], acc[8][4];
#pragma unroll
  for (int i = 0; i < 8; ++i)
#pragma unroll
    for (int j2 = 0; j2 < 4; ++j2) { accT[i][j2] = 0.f; acc[i][j2] = 0.f; }

  float4 av[4], bv[2];
#pragma unroll
  for (int it = 0; it < 4; ++it) {
    int id = tid + it * 256;
    av[it] = *(const float4*)(A + (size_t)(m0 + (id >> 3)) * 1024 + ((id & 7) << 2));
  }
#pragma unroll
  for (int it = 0; it < 2; ++it) {
    int id = tid + it * 256;
    bv[it] = *(const float4*)(W + (size_t)(id >> 4) * 1024 + n0 + ((id & 15) << 2));
  }
  for (int kk = 0; kk < 1024; kk += 32) {
#pragma unroll
    for (int it = 0; it < 4; ++it) {
      int id = tid + it * 256;
      int m = id >> 3, kq = (id & 7) << 2;
      As[kq + 0][m] = av[it].x;
      As[kq + 1][m] = av[it].y;
      As[kq + 2][m] = av[it].z;
      As[kq + 3][m] = av[it].w;
    }
#pragma unroll
    for (int it = 0; it < 2; ++it) {
      int id = tid + it * 256;
      *(float4*)&Bs[id >> 4][(id & 15) << 2] = bv[it];
    }
    __syncthreads();
    if (kk + 32 < 1024) {
      int kn = kk + 32;
#pragma unroll
      for (int it = 0; it < 4; ++it) {
        int id = tid + it * 256;
        av[it] = *(const float4*)(A + (size_t)(m0 + (id >> 3)) * 1024 + kn + ((id & 7) << 2));
      }
#pragma unroll
      for (int it = 0; it < 2; ++it) {
        int id = tid + it * 256;
        bv[it] = *(const float4*)(W + (size_t)(kn + (id >> 4)) * 1024 + n0 + ((id & 15) << 2));
      }
    }
#pragma unroll
    for (int k = 0; k < 32; ++k) {
      float4 a0 = *(const float4*)&As[k][tr * 8];
      float4 a1 = *(const float4*)&As[k][tr * 8 + 4];
      float4 b0 = *(const float4*)&Bs[k][tc * 4];
      float a[8] = {a0.x, a0.y, a0.z, a0.w, a1.x, a1.y, a1.z, a1.w};
      float b[4] = {b0.x, b0.y, b0.z, b0.w};
#pragma unroll
      for (int i = 0; i < 8; ++i)
#pragma unroll
        for (int j2 = 0; j2 < 4; ++j2)
          acc[i][j2] = fmaf(a[i], b[j2], acc[i][j2]);
    }
    __syncthreads();
    if (((kk + 32) % KC_BLOCK) == 0) {
#pragma unroll
      for (int i = 0; i < 8; ++i)
#pragma unroll
        for (int j2 = 0; j2 < 4; ++j2) { accT[i][j2] += acc[i][j2]; acc[i][j2] = 0.f; }
    }
  }
#pragma unroll
  for (int i = 0; i < 8; ++i)
#pragma unroll
    for (int j2 = 0; j2 < 4; ++j2) accT[i][j2] += acc[i][j2];

  const int h = n0 >> 6;
  const int d = tc << 2;
#pragma unroll
  for (int i = 0; i < 8; ++i) {
    int m = m0 + tr * 8 + i;
    int b = m >> 12, s = m & 4095;
    float4 t = {accT[i][0], accT[i][1], accT[i][2], accT[i][3]};
    *(float4*)(dst + (((size_t)(b * 16 + h) * 4096 + s) << 6) + d) = t;
  }
}

// ---------------- f32 -> bf16 (RNE) cast ----------------
__device__ __forceinline__ unsigned short f2bf(float f) {
  unsigned u = __float_as_uint(f);
  return (unsigned short)((u + 0x7fffu + ((u >> 16) & 1u)) >> 16);
}
__global__ void cast_bf16_kernel(const float* __restrict__ src,
                                 unsigned short* __restrict__ dst, int n4) {
  int i = blockIdx.x * 256 + threadIdx.x;
  if (i >= n4) return;
  float4 v = ((const float4*)src)[i];
  ushort4 o = {f2bf(v.x), f2bf(v.y), f2bf(v.z), f2bf(v.w)};
  ((ushort4*)dst)[i] = o;
}

// ---------------- V GEMM via bf16 MFMA -> bf16 output (smooth path) --------
typedef __attribute__((ext_vector_type(8))) short bf16x8;
typedef __attribute__((ext_vector_type(4))) float f32x4;

__global__ __launch_bounds__(256) void gemm_v_mfma(const unsigned short* __restrict__ Ab,
                                                   const unsigned short* __restrict__ Wb,
                                                   unsigned short* __restrict__ dst) {
  __shared__ unsigned short Bt[64][40];
  const int m0 = blockIdx.x * 64;
  const int n0 = blockIdx.y * 64;
  const int tid = threadIdx.x;
  const int w = tid >> 6, l = tid & 63;
  f32x4 acc[4];
#pragma unroll
  for (int fi = 0; fi < 4; ++fi) acc[fi] = {0.f, 0.f, 0.f, 0.f};

  const int arow = m0 + w * 16 + (l & 15);
  const int kgrp = (l >> 4) * 8;
  for (int kk = 0; kk < 1024; kk += 32) {
    {
      int k = tid >> 3, n8 = (tid & 7) * 8;
      bf16x8 v = *(const bf16x8*)(Wb + (size_t)(kk + k) * 1024 + n0 + n8);
#pragma unroll
      for (int i = 0; i < 8; ++i) Bt[n8 + i][k] = (unsigned short)v[i];
    }
    __syncthreads();
    bf16x8 a = *(const bf16x8*)(Ab + (size_t)arow * 1024 + kk + kgrp);
#pragma unroll
    for (int fi = 0; fi < 4; ++fi) {
      bf16x8 b = *(const bf16x8*)(&Bt[fi * 16 + (l & 15)][kgrp]);
      acc[fi] = __builtin_amdgcn_mfma_f32_16x16x32_bf16(a, b, acc[fi], 0, 0, 0);
    }
    __syncthreads();
  }
  const int h = n0 >> 6;
  const int mrow = m0 + w * 16 + (l >> 4) * 4;
#pragma unroll
  for (int fi = 0; fi < 4; ++fi) {
    int d = fi * 16 + (l & 15);
#pragma unroll
    for (int r = 0; r < 4; ++r) {
      int m = mrow + r;
      int b = m >> 12, s = m & 4095;
      dst[(((size_t)(b * 16 + h) * 4096 + s) << 6) + d] = f2bf(acc[fi][r]);
    }
  }
}

// ---------------- LSH hash (FROZEN numerics) ----------
__global__ __launch_bounds__(128) void hash_kernel(const float* __restrict__ x,
                                                   const float* __restrict__ rot,
                                                   int* __restrict__ buck) {
  __shared__ float rs[8192];
  const int bh = blockIdx.y;
  const int h = bh & 15;
  const int s0 = blockIdx.x * 128;
  const int tid = threadIdx.x;
  for (int off = tid * 4; off < 8192; off += 512)
    *(float4*)&rs[off] = *(const float4*)(rot + (size_t)h * 8192 + off);
  __syncthreads();
  const int s = s0 + tid;
  const float* xr = x + ((size_t)bh * SS + s) * DD;
  float xv[64];
#pragma unroll
  for (int d4 = 0; d4 < 16; ++d4) {
    float4 t = *(const float4*)(xr + d4 * 4);
    xv[d4 * 4] = t.x; xv[d4 * 4 + 1] = t.y; xv[d4 * 4 + 2] = t.z; xv[d4 * 4 + 3] = t.w;
  }
#pragma unroll
  for (int n = 0; n < 2; ++n) {
    float acc[64];
#pragma unroll
    for (int r = 0; r < 64; ++r) acc[r] = 0.f;
#pragma unroll 2
    for (int d4 = 0; d4 < 16; ++d4) {
#pragma unroll
      for (int dd = 0; dd < 4; ++dd) {
        const float xd = xv[d4 * 4 + dd];
        const float* rp = rs + (d4 * 4 + dd) * 128 + n * 64;
#pragma unroll
        for (int r4 = 0; r4 < 16; ++r4) {
          float4 rv = *(const float4*)(rp + r4 * 4);
          acc[r4 * 4 + 0] = fmaf(xd, rv.x, acc[r4 * 4 + 0]);
          acc[r4 * 4 + 1] = fmaf(xd, rv.y, acc[r4 * 4 + 1]);
          acc[r4 * 4 + 2] = fmaf(xd, rv.z, acc[r4 * 4 + 2]);
          acc[r4 * 4 + 3] = fmaf(xd, rv.w, acc[r4 * 4 + 3]);
        }
      }
    }
    float best = -3.402823466e38f;
    int bi = 0;
#pragma unroll
    for (int idx = 0; idx < 128; ++idx) {
      float val = (idx < 64) ? acc[idx] : -acc[idx - 64];
      if (val > best) { best = val; bi = idx; }
    }
    buck[(size_t)bh * NSORT + n * SS + s] = bi + n * NBUCK;
  }
}

// ---------------- parallel stable counting sort ----------------
__global__ __launch_bounds__(256) void sort_kernel(const int* __restrict__ buck,
                                                   int* __restrict__ sorted) {
  const int bh = blockIdx.x >> 1;
  const int half = blockIdx.x & 1;
  const int* bk = buck + (size_t)bh * NSORT + half * SS;
  int* out = sorted + (size_t)bh * NSORT + half * SS;
  __shared__ int cnt[64][128];
  __shared__ int bl[SS];
  __shared__ int bbase[128];
  __shared__ int total[128];
  const int tid = threadIdx.x;
  for (int i = tid; i < 64 * 128; i += 256) (&cnt[0][0])[i] = 0;
  __syncthreads();
#pragma unroll
  for (int j = 0; j < 16; ++j) {
    int i = j * 256 + tid;
    int e = bk[i];
    bl[i] = e;
    atomicAdd(&cnt[i >> 6][e & 127], 1);
  }
  __syncthreads();
  if (tid < 128) {
    int s = 0;
#pragma unroll 4
    for (int c = 0; c < 64; ++c) {
      int t = cnt[c][tid];
      cnt[c][tid] = s;
      s += t;
    }
    total[tid] = s;
  }
  __syncthreads();
  if (tid == 0) {
    int s = 0;
#pragma unroll 4
    for (int v = 0; v < 128; ++v) { bbase[v] = s; s += total[v]; }
  }
  __syncthreads();
  if (tid < 64) {
    const int i0 = tid << 6;
    const int orig0 = half * SS + i0;
#pragma unroll 4
    for (int j = 0; j < 64; ++j) {
      int v = bl[i0 + j] & 127;
      int off = cnt[tid][v];
      cnt[tid][v] = off + 1;
      out[bbase[v] + off] = orig0 + j;
    }
  }
}

// ---------------- undo indices: undo[srt[j]] = j ----------------
__global__ void undo_kernel(const int* __restrict__ srt, int* __restrict__ undo) {
  const int bh = blockIdx.x;
  for (int j = threadIdx.x; j < NSORT; j += 256)
    undo[(size_t)bh * NSORT + srt[(size_t)bh * NSORT + j]] = j;
}

// ---------------- MFMA chunked attention (smooth path, bf16) ----------------
// 256 threads = 4 waves; wave w owns q-rows [w*16, w*16+16).
// Fragment layouts replicate the VERIFIED gemm_v_mfma pattern:
//   A-frag: row = base + (l&15), k = (l>>4)*8..+7 (bf16x8)
//   B-frag: col = base + (l&15), same k      (B stored [n][k])
//   D-frag: col = fi*16 + (l&15), row = (l>>4)*4 + r
__global__ __launch_bounds__(256) void attn_mfma_kernel(
    const unsigned short* __restrict__ qb16, const unsigned short* __restrict__ kb16,
    const unsigned short* __restrict__ vb16,
    const int* __restrict__ sq, const int* __restrict__ sk,
    float* __restrict__ outr, float* __restrict__ lr) {
  const int c = blockIdx.x, bh = blockIdx.y;
  const int cprev = (c + NCHUNKS - 1) & (NCHUNKS - 1);
  __shared__ unsigned short Qs[64][80];     // [q-row][d]
  __shared__ unsigned short Ks[128][80];    // [key][d]
  __shared__ unsigned short Vt[64][136];    // [d][key]
  __shared__ unsigned short Ps[64][136];    // [q-row][key] unnormalized exp
  __shared__ int qpos[64];
  __shared__ int kvpos[128];
  __shared__ int krow[128];
  __shared__ float kscale[128];
  const int tid = threadIdx.x;
  const int* sqb = sq + (size_t)bh * NSORT;
  const int* skb = sk + (size_t)bh * NSORT;
  if (tid < 64) {
    int sqc = sqb[c * 64 + tid];
    int sqp = sqb[cprev * 64 + tid];
    qpos[tid] = sqc & (SS - 1);
    kvpos[tid] = sqp & (SS - 1);
    kvpos[64 + tid] = sqc & (SS - 1);
    krow[tid] = skb[cprev * 64 + tid] & (SS - 1);
    krow[64 + tid] = skb[c * 64 + tid] & (SS - 1);
  }
  __syncthreads();
  const unsigned short* kbase = kb16 + (size_t)bh * SS * DD;
  const unsigned short* vbase = vb16 + (size_t)bh * SS * DD;
  const unsigned short* qbase = qb16 + (size_t)bh * SS * DD;
#pragma unroll
  for (int it = 0; it < 4; ++it) {
    int id = tid + it * 256;
    int row = id >> 3, seg = id & 7;
    *(bf16x8*)&Ks[row][seg * 8] = *(const bf16x8*)(kbase + (size_t)krow[row] * DD + seg * 8);
  }
#pragma unroll
  for (int it = 0; it < 2; ++it) {
    int id = tid + it * 256;
    int row = id >> 3, seg = id & 7;
    *(bf16x8*)&Qs[row][seg * 8] = *(const bf16x8*)(qbase + (size_t)qpos[row] * DD + seg * 8);
  }
#pragma unroll
  for (int it = 0; it < 4; ++it) {
    int id = tid + it * 256;
    int col = id & 127, dg = id >> 7;
    bf16x8 v = *(const bf16x8*)(vbase + (size_t)krow[col] * DD + dg * 8);
#pragma unroll
    for (int i = 0; i < 8; ++i) Vt[dg * 8 + i][col] = (unsigned short)v[i];
  }
  __syncthreads();
  if (tid < 128) {
    float ss = 0.f;
#pragma unroll
    for (int seg = 0; seg < 8; ++seg) {
      bf16x8 t = *(const bf16x8*)&Ks[tid][seg * 8];
#pragma unroll
      for (int i = 0; i < 8; ++i) {
        float f = __uint_as_float(((unsigned)(unsigned short)t[i]) << 16);
        ss = fmaf(f, f, ss);
      }
    }
    kscale[tid] = rsqrtf(ss * (1.f / 64.f) + 1e-6f) * 0.125f;
  }
  __syncthreads();

  const int w = tid >> 6, l = tid & 63;
  const int lc = l & 15, lg = l >> 4;
  // ---- QK^T
  bf16x8 a0 = *(const bf16x8*)&Qs[w * 16 + lc][lg * 8];
  bf16x8 a1 = *(const bf16x8*)&Qs[w * 16 + lc][32 + lg * 8];
  f32x4 accs[8];
#pragma unroll
  for (int fi = 0; fi < 8; ++fi) {
    f32x4 acc = {0.f, 0.f, 0.f, 0.f};
    bf16x8 b0 = *(const bf16x8*)&Ks[fi * 16 + lc][lg * 8];
    bf16x8 b1 = *(const bf16x8*)&Ks[fi * 16 + lc][32 + lg * 8];
    acc = __builtin_amdgcn_mfma_f32_16x16x32_bf16(a0, b0, acc, 0, 0, 0);
    acc = __builtin_amdgcn_mfma_f32_16x16x32_bf16(a1, b1, acc, 0, 0, 0);
    accs[fi] = acc;
  }
  // ---- scale, self-mask, softmax
  float kcs[8]; int kvp[8];
#pragma unroll
  for (int fi = 0; fi < 8; ++fi) { kcs[fi] = kscale[fi * 16 + lc]; kvp[fi] = kvpos[fi * 16 + lc]; }
  float ex[8][4], logit_r[4], seinv_r[4];
#pragma unroll
  for (int r = 0; r < 4; ++r) {
    const int qp = qpos[w * 16 + lg * 4 + r];
    float mr = -3.402823466e38f;
#pragma unroll
    for (int fi = 0; fi < 8; ++fi) {
      float d = accs[fi][r] * kcs[fi];
      if (qp == kvp[fi]) d = -1e5f;
      ex[fi][r] = d;
      mr = fmaxf(mr, d);
    }
    mr = fmaxf(mr, __shfl_xor(mr, 1));
    mr = fmaxf(mr, __shfl_xor(mr, 2));
    mr = fmaxf(mr, __shfl_xor(mr, 4));
    mr = fmaxf(mr, __shfl_xor(mr, 8));
    float s = 0.f;
#pragma unroll
    for (int fi = 0; fi < 8; ++fi) { float e = expf(ex[fi][r] - mr); ex[fi][r] = e; s += e; }
    s += __shfl_xor(s, 1);
    s += __shfl_xor(s, 2);
    s += __shfl_xor(s, 4);
    s += __shfl_xor(s, 8);
    logit_r[r] = mr + logf(s);
    seinv_r[r] = 1.f / s;
  }
#pragma unroll
  for (int r = 0; r < 4; ++r) {
    int row = w * 16 + lg * 4 + r;
#pragma unroll
    for (int fi = 0; fi < 8; ++fi)
      Ps[row][fi * 16 + lc] = f2bf(ex[fi][r]);
    if (lc == 0) lr[(size_t)bh * NSORT + c * 64 + row] = logit_r[r];
  }
  __syncthreads();
  // ---- PV
  f32x4 acco[4];
#pragma unroll
  for (int fi2 = 0; fi2 < 4; ++fi2) acco[fi2] = {0.f, 0.f, 0.f, 0.f};
#pragma unroll
  for (int kg = 0; kg < 4; ++kg) {
    bf16x8 a = *(const bf16x8*)&Ps[w * 16 + lc][kg * 32 + lg * 8];
#pragma unroll
    for (int fi2 = 0; fi2 < 4; ++fi2) {
      bf16x8 b = *(const bf16x8*)&Vt[fi2 * 16 + lc][kg * 32 + lg * 8];
      acco[fi2] = __builtin_amdgcn_mfma_f32_16x16x32_bf16(a, b, acco[fi2], 0, 0, 0);
    }
  }
#pragma unroll
  for (int fi2 = 0; fi2 < 4; ++fi2) {
    int d = fi2 * 16 + lc;
#pragma unroll
    for (int r = 0; r < 4; ++r) {
      int row = w * 16 + lg * 4 + r;
      outr[((size_t)bh * NSORT + c * 64 + row) * DD + d] = acco[fi2][r] * seinv_r[r];
    }
  }
}

// ---------------- merge: undo-gather + round-logsumexp + transpose ------
__global__ void merge_kernel(const float* __restrict__ outr, const float* __restrict__ lr,
                             const int* __restrict__ undo, float* __restrict__ out) {
  const int idx = blockIdx.x * 256 + threadIdx.x;   // over B*H*S*16
  const int d4 = idx & 15;
  const int s = (idx >> 4) & (SS - 1);
  const int bh = idx >> 16;
  const int b = bh >> 4, h = bh & 15;
  const int u0 = undo[(size_t)bh * NSORT + s];
  const int u1 = undo[(size_t)bh * NSORT + SS + s];
  const float l0 = lr[(size_t)bh * NSORT + u0];
  const float l1 = lr[(size_t)bh * NSORT + u1];
  const float m = fmaxf(l0, l1);
  float w0 = expf(l0 - m), w1 = expf(l1 - m);
  const float inv = 1.f / (w0 + w1);
  w0 *= inv; w1 *= inv;
  const float4 r0 = *(const float4*)(outr + ((size_t)bh * NSORT + u0) * DD + d4 * 4);
  const float4 r1 = *(const float4*)(outr + ((size_t)bh * NSORT + u1) * DD + d4 * 4);
  float4 o;
  o.x = w0 * r0.x + w1 * r1.x;
  o.y = w0 * r0.y + w1 * r1.y;
  o.z = w0 * r0.z + w1 * r1.z;
  o.w = w0 * r0.w + w1 * r1.w;
  *(float4*)(out + ((size_t)(b * SS + s) * 1024) + h * 64 + d4 * 4) = o;
}

extern "C" void kernel_launch(void* const* d_in, const int* in_sizes, int n_in,
                              void* d_out, int out_size, void* d_ws, size_t ws_size,
                              hipStream_t stream) {
  if (ws_size < WS_REQUIRED) return;
  const float* dec = (const float*)d_in[0];
  const float* hid = (const float*)d_in[1];
  const float* wqk = (const float*)d_in[2];
  const float* wv  = (const float*)d_in[3];
  float* out = (float*)d_out;
  char* ws = (char*)d_ws;
  float* q    = (float*)(ws + OFF_Q);
  float* kk   = (float*)(ws + OFF_K);
  unsigned short* vbf = (unsigned short*)(ws + OFF_V);
  float* rotp = (float*)(ws + OFF_ROT);
  int*   qb   = (int*)(ws + OFF_QB);    // q-buckets, then undo_k
  int*   kbk  = (int*)(ws + OFF_KB);
  int*   sqi  = (int*)(ws + OFF_SQ);
  int*   ski  = (int*)(ws + OFF_SK);
  float* outr = (float*)(ws + OFF_OUTR);
  float* lrp  = (float*)(ws + OFF_LR);
  unsigned short* hbf = (unsigned short*)(ws + OFF_HBF);
  unsigned short* wbf = (unsigned short*)(ws + OFF_WBF);
  unsigned short* qbf = (unsigned short*)(ws + OFF_QBF);
  unsigned short* kbf = (unsigned short*)(ws + OFF_KBF);

  gen_rot_kernel<<<512, 256, 0, stream>>>(rotp);
  cast_bf16_kernel<<<8192, 256, 0, stream>>>(hid, hbf, 8192 * 1024 / 4);
  cast_bf16_kernel<<<1024, 256, 0, stream>>>(wv, wbf, 1024 * 1024 / 4);
  gemm_kernel<<<dim3(64, 16), 256, 0, stream>>>(dec, wqk, q);
  gemm_kernel<<<dim3(64, 16), 256, 0, stream>>>(hid, wqk, kk);
  gemm_v_mfma<<<dim3(128, 16), 256, 0, stream>>>(hbf, wbf, vbf);
  hash_kernel<<<dim3(32, 32), 128, 0, stream>>>(q, rotp, qb);
  hash_kernel<<<dim3(32, 32), 128, 0, stream>>>(kk, rotp, kbk);
  cast_bf16_kernel<<<8192, 256, 0, stream>>>(q, qbf, 8192 * 1024 / 4);
  cast_bf16_kernel<<<8192, 256, 0, stream>>>(kk, kbf, 8192 * 1024 / 4);
  sort_kernel<<<64, 256, 0, stream>>>(qb, sqi);
  sort_kernel<<<64, 256, 0, stream>>>(kbk, ski);
  undo_kernel<<<32, 256, 0, stream>>>(ski, qb);   // qb now holds undo_k
  attn_mfma_kernel<<<dim3(128, 32), 256, 0, stream>>>(qbf, kbf, vbf, sqi, ski, outr, lrp);
  merge_kernel<<<8192, 256, 0, stream>>>(outr, lrp, qb, out);
}

// Round 18
// 801.854 us; speedup vs baseline: 2.0790x; 1.0308x over previous
//
#include <hip/hip_runtime.h>
#include <cstdint>
#include <cstddef>

// Problem constants
#define BB 2
#define SS 4096
#define HH 16
#define DD 64
#define HID 1024
#define NHASH 2
#define CHUNK 64
#define NBUCK 128
#define NCHUNKS 128
#define NSORT 8192
#define BHN 32

// Eigen gebp kc blocking (l1=32KB, f32 AVX2: mr=24,nr=4 -> 288). FROZEN: bucket path.
#define KC_BLOCK 288

// ---------------- workspace layout ----------------
static constexpr size_t SZ_QKV  = (size_t)BB*HH*SS*DD*4;             // 32 MB
static constexpr size_t OFF_Q   = 0;
static constexpr size_t OFF_K   = OFF_Q + SZ_QKV;
static constexpr size_t OFF_V   = OFF_K + SZ_QKV;                    // V bf16 (16MB used)
static constexpr size_t OFF_ROT = OFF_V + SZ_QKV;
static constexpr size_t OFF_QB  = OFF_ROT + (size_t)131072*4;        // q-buckets (scratch)
static constexpr size_t OFF_KB  = OFF_QB + (size_t)BHN*NSORT*4;      // k-buckets -> undo_k
static constexpr size_t OFF_SQ  = OFF_KB + (size_t)BHN*NSORT*4;
static constexpr size_t OFF_SK  = OFF_SQ + (size_t)BHN*NSORT*4;
static constexpr size_t OFF_OUTR= OFF_SK + (size_t)BHN*NSORT*4;      // attn out, SORTED rows
static constexpr size_t OFF_LR  = OFF_OUTR + (size_t)BHN*NSORT*DD*4; // logits, SORTED rows
static constexpr size_t OFF_QBF = OFF_LR + (size_t)BHN*NSORT*4;      // q as bf16 (16MB)
static constexpr size_t OFF_KBF = OFF_QBF + (size_t)BHN*SS*DD*2;     // k as bf16 (16MB)
static constexpr size_t WS_REQUIRED = OFF_KBF + (size_t)BHN*SS*DD*2;

// ---------------- XLA f32 helpers (FROZEN: bucket path) ----------------
__device__ __forceinline__ float nofma_mul(float a, float b) {
  float r = a * b;
  asm("" : "+v"(r));
  return r;
}

__device__ __forceinline__ float xla_log1p_f32(float x) {
  float t = nofma_mul(-0.5f, x) + 1.0f;
  float small = nofma_mul(t, x);
  float onep = 1.0f + x;
  float big = (float)log((double)onep);
  return (fabsf(x) < 1e-4f) ? small : big;
}

__device__ __forceinline__ float erfinv_xla_f32(float x) {
  float nxx = -nofma_mul(x, x);
  float w = -xla_log1p_f32(nxx);
  float p;
  if (w < 5.0f) {
    float ww = w - 2.5f;
    p = 2.81022636e-08f;
    p = nofma_mul(p, ww) + 3.43273939e-07f;
    p = nofma_mul(p, ww) + -3.5233877e-06f;
    p = nofma_mul(p, ww) + -4.39150654e-06f;
    p = nofma_mul(p, ww) + 0.00021858087f;
    p = nofma_mul(p, ww) + -0.00125372503f;
    p = nofma_mul(p, ww) + -0.00417768164f;
    p = nofma_mul(p, ww) + 0.246640727f;
    p = nofma_mul(p, ww) + 1.50140941f;
  } else {
    float ww = sqrtf(w) - 3.0f;
    p = -0.000200214257f;
    p = nofma_mul(p, ww) + 0.000100950558f;
    p = nofma_mul(p, ww) + 0.00134934322f;
    p = nofma_mul(p, ww) + -0.00367342844f;
    p = nofma_mul(p, ww) + 0.00573950773f;
    p = nofma_mul(p, ww) + -0.0076224613f;
    p = nofma_mul(p, ww) + 0.00943887047f;
    p = nofma_mul(p, ww) + 1.00167406f;
    p = nofma_mul(p, ww) + 2.83297682f;
  }
  return nofma_mul(p, x);
}

// rotations via threefry2x32 partitionable stream (FROZEN)
__global__ void gen_rot_kernel(float* __restrict__ rot) {
  unsigned i = blockIdx.x * 256 + threadIdx.x;
  if (i >= 131072u) return;
  unsigned x0 = 0u, x1 = i;
  const unsigned ks2 = 0x1BD11BDAu;
#define TF_ROUND(r) { x0 += x1; x1 = (x1 << r) | (x1 >> (32 - r)); x1 ^= x0; }
  TF_ROUND(13) TF_ROUND(15) TF_ROUND(26) TF_ROUND(6)
  /* g=1 */            x1 += ks2 + 1u;
  TF_ROUND(17) TF_ROUND(29) TF_ROUND(16) TF_ROUND(24)
  /* g=2 */ x0 += ks2; x1 += 2u;
  TF_ROUND(13) TF_ROUND(15) TF_ROUND(26) TF_ROUND(6)
  /* g=3 */            x1 += 3u;
  TF_ROUND(17) TF_ROUND(29) TF_ROUND(16) TF_ROUND(24)
  /* g=4 */            x1 += ks2 + 4u;
  TF_ROUND(13) TF_ROUND(15) TF_ROUND(26) TF_ROUND(6)
  /* g=5 */ x0 += ks2; x1 += 5u;
#undef TF_ROUND
  unsigned bits = x0 ^ x1;
  float f = __uint_as_float(0x3f800000u | (bits >> 9)) - 1.0f;
  float u = f * 2.0f - 0.99999994f;
  u = fmaxf(-0.99999994f, u);
  rot[i] = nofma_mul(1.41421356f, erfinv_xla_f32(u));
}

// ---------------- f32 -> bf16 (RNE) ----------------
__device__ __forceinline__ unsigned short f2bf(float f) {
  unsigned u = __float_as_uint(f);
  return (unsigned short)((u + 0x7fffu + ((u >> 16) & 1u)) >> 16);
}

// ---------------- f32 GEMM (Q,K), Eigen kc=288-blocked (R12 numerics) ------
// 128x64 tile, BK=32, 256 threads, 8x4 micro, strides 132/68, VGPR ~116.
// Epilogue dual-writes f32 (hash path) and bf16 (attn path).
__global__ __launch_bounds__(256) void gemm_kernel(const float* __restrict__ A,
                                                   const float* __restrict__ W,
                                                   float* __restrict__ dst,
                                                   unsigned short* __restrict__ dstb) {
  __shared__ float As[32][132];
  __shared__ float Bs[32][68];
  const int m0 = blockIdx.x * 128;
  const int n0 = blockIdx.y * 64;
  const int tid = threadIdx.x;
  const int tr = tid >> 4, tc = tid & 15;
  float accT[8][4], acc[8][4];
#pragma unroll
  for (int i = 0; i < 8; ++i)
#pragma unroll
    for (int j2 = 0; j2 < 4; ++j2) { accT[i][j2] = 0.f; acc[i][j2] = 0.f; }

  float4 av[4], bv[2];
#pragma unroll
  for (int it = 0; it < 4; ++it) {
    int id = tid + it * 256;
    av[it] = *(const float4*)(A + (size_t)(m0 + (id >> 3)) * 1024 + ((id & 7) << 2));
  }
#pragma unroll
  for (int it = 0; it < 2; ++it) {
    int id = tid + it * 256;
    bv[it] = *(const float4*)(W + (size_t)(id >> 4) * 1024 + n0 + ((id & 15) << 2));
  }
  for (int kk = 0; kk < 1024; kk += 32) {
#pragma unroll
    for (int it = 0; it < 4; ++it) {
      int id = tid + it * 256;
      int m = id >> 3, kq = (id & 7) << 2;
      As[kq + 0][m] = av[it].x;
      As[kq + 1][m] = av[it].y;
      As[kq + 2][m] = av[it].z;
      As[kq + 3][m] = av[it].w;
    }
#pragma unroll
    for (int it = 0; it < 2; ++it) {
      int id = tid + it * 256;
      *(float4*)&Bs[id >> 4][(id & 15) << 2] = bv[it];
    }
    __syncthreads();
    if (kk + 32 < 1024) {
      int kn = kk + 32;
#pragma unroll
      for (int it = 0; it < 4; ++it) {
        int id = tid + it * 256;
        av[it] = *(const float4*)(A + (size_t)(m0 + (id >> 3)) * 1024 + kn + ((id & 7) << 2));
      }
#pragma unroll
      for (int it = 0; it < 2; ++it) {
        int id = tid + it * 256;
        bv[it] = *(const float4*)(W + (size_t)(kn + (id >> 4)) * 1024 + n0 + ((id & 15) << 2));
      }
    }
#pragma unroll
    for (int k = 0; k < 32; ++k) {     // k strictly ascending: order-exact
      float4 a0 = *(const float4*)&As[k][tr * 8];
      float4 a1 = *(const float4*)&As[k][tr * 8 + 4];
      float4 b0 = *(const float4*)&Bs[k][tc * 4];
      float a[8] = {a0.x, a0.y, a0.z, a0.w, a1.x, a1.y, a1.z, a1.w};
      float b[4] = {b0.x, b0.y, b0.z, b0.w};
#pragma unroll
      for (int i = 0; i < 8; ++i)
#pragma unroll
        for (int j2 = 0; j2 < 4; ++j2)
          acc[i][j2] = fmaf(a[i], b[j2], acc[i][j2]);
    }
    __syncthreads();
    if (((kk + 32) % KC_BLOCK) == 0) {  // folds at 288/576/864
#pragma unroll
      for (int i = 0; i < 8; ++i)
#pragma unroll
        for (int j2 = 0; j2 < 4; ++j2) { accT[i][j2] += acc[i][j2]; acc[i][j2] = 0.f; }
    }
  }
#pragma unroll
  for (int i = 0; i < 8; ++i)
#pragma unroll
    for (int j2 = 0; j2 < 4; ++j2) accT[i][j2] += acc[i][j2];   // tail (160)

  const int h = n0 >> 6;
  const int d = tc << 2;
#pragma unroll
  for (int i = 0; i < 8; ++i) {
    int m = m0 + tr * 8 + i;
    int b = m >> 12, s = m & 4095;
    size_t base = (((size_t)(b * 16 + h) * 4096 + s) << 6) + d;
    float4 t = {accT[i][0], accT[i][1], accT[i][2], accT[i][3]};
    *(float4*)(dst + base) = t;
    ushort4 tb = {f2bf(t.x), f2bf(t.y), f2bf(t.z), f2bf(t.w)};
    *(ushort4*)(dstb + base) = tb;
  }
}

// ---------------- V GEMM via bf16 MFMA, f32 inputs converted inline --------
typedef __attribute__((ext_vector_type(8))) short bf16x8;
typedef __attribute__((ext_vector_type(4))) float f32x4;

__device__ __forceinline__ bf16x8 cvt8(float4 lo, float4 hi) {
  bf16x8 r;
  r[0] = (short)f2bf(lo.x); r[1] = (short)f2bf(lo.y);
  r[2] = (short)f2bf(lo.z); r[3] = (short)f2bf(lo.w);
  r[4] = (short)f2bf(hi.x); r[5] = (short)f2bf(hi.y);
  r[6] = (short)f2bf(hi.z); r[7] = (short)f2bf(hi.w);
  return r;
}

__global__ __launch_bounds__(256) void gemm_v_mfma(const float* __restrict__ Af,
                                                   const float* __restrict__ Wf,
                                                   unsigned short* __restrict__ dst) {
  __shared__ unsigned short Bt[64][40];
  const int m0 = blockIdx.x * 64;
  const int n0 = blockIdx.y * 64;
  const int tid = threadIdx.x;
  const int w = tid >> 6, l = tid & 63;
  f32x4 acc[4];
#pragma unroll
  for (int fi = 0; fi < 4; ++fi) acc[fi] = {0.f, 0.f, 0.f, 0.f};

  const int arow = m0 + w * 16 + (l & 15);
  const int kgrp = (l >> 4) * 8;
  for (int kk = 0; kk < 1024; kk += 32) {
    {   // stage Bt[n][k] = bf16(Wf[kk+k][n0+n])
      int k = tid >> 3, n8 = (tid & 7) * 8;
      const float* wp = Wf + (size_t)(kk + k) * 1024 + n0 + n8;
      bf16x8 v = cvt8(*(const float4*)wp, *(const float4*)(wp + 4));
#pragma unroll
      for (int i = 0; i < 8; ++i) Bt[n8 + i][k] = (unsigned short)v[i];
    }
    __syncthreads();
    const float* ap = Af + (size_t)arow * 1024 + kk + kgrp;
    bf16x8 a = cvt8(*(const float4*)ap, *(const float4*)(ap + 4));
#pragma unroll
    for (int fi = 0; fi < 4; ++fi) {
      bf16x8 b = *(const bf16x8*)(&Bt[fi * 16 + (l & 15)][kgrp]);
      acc[fi] = __builtin_amdgcn_mfma_f32_16x16x32_bf16(a, b, acc[fi], 0, 0, 0);
    }
    __syncthreads();
  }
  const int h = n0 >> 6;
  const int mrow = m0 + w * 16 + (l >> 4) * 4;
#pragma unroll
  for (int fi = 0; fi < 4; ++fi) {
    int d = fi * 16 + (l & 15);
#pragma unroll
    for (int r = 0; r < 4; ++r) {
      int m = mrow + r;
      int b = m >> 12, s = m & 4095;
      dst[(((size_t)(b * 16 + h) * 4096 + s) << 6) + d] = f2bf(acc[fi][r]);
    }
  }
}

// ---------------- LSH hash (FROZEN numerics) ----------
__global__ __launch_bounds__(128) void hash_kernel(const float* __restrict__ x,
                                                   const float* __restrict__ rot,
                                                   int* __restrict__ buck) {
  __shared__ float rs[8192];
  const int bh = blockIdx.y;
  const int h = bh & 15;
  const int s0 = blockIdx.x * 128;
  const int tid = threadIdx.x;
  for (int off = tid * 4; off < 8192; off += 512)
    *(float4*)&rs[off] = *(const float4*)(rot + (size_t)h * 8192 + off);
  __syncthreads();
  const int s = s0 + tid;
  const float* xr = x + ((size_t)bh * SS + s) * DD;
  float xv[64];
#pragma unroll
  for (int d4 = 0; d4 < 16; ++d4) {
    float4 t = *(const float4*)(xr + d4 * 4);
    xv[d4 * 4] = t.x; xv[d4 * 4 + 1] = t.y; xv[d4 * 4 + 2] = t.z; xv[d4 * 4 + 3] = t.w;
  }
#pragma unroll
  for (int n = 0; n < 2; ++n) {
    float acc[64];
#pragma unroll
    for (int r = 0; r < 64; ++r) acc[r] = 0.f;
#pragma unroll 2
    for (int d4 = 0; d4 < 16; ++d4) {
#pragma unroll
      for (int dd = 0; dd < 4; ++dd) {
        const float xd = xv[d4 * 4 + dd];
        const float* rp = rs + (d4 * 4 + dd) * 128 + n * 64;
#pragma unroll
        for (int r4 = 0; r4 < 16; ++r4) {
          float4 rv = *(const float4*)(rp + r4 * 4);
          acc[r4 * 4 + 0] = fmaf(xd, rv.x, acc[r4 * 4 + 0]);
          acc[r4 * 4 + 1] = fmaf(xd, rv.y, acc[r4 * 4 + 1]);
          acc[r4 * 4 + 2] = fmaf(xd, rv.z, acc[r4 * 4 + 2]);
          acc[r4 * 4 + 3] = fmaf(xd, rv.w, acc[r4 * 4 + 3]);
        }
      }
    }
    float best = -3.402823466e38f;
    int bi = 0;
#pragma unroll
    for (int idx = 0; idx < 128; ++idx) {
      float val = (idx < 64) ? acc[idx] : -acc[idx - 64];
      if (val > best) { best = val; bi = idx; }
    }
    buck[(size_t)bh * NSORT + n * SS + s] = bi + n * NBUCK;
  }
}

// ---------------- parallel stable counting sort (+ inline undo) ----------
// In-place-safe: each block reads only its own (bh,half) segment (staged to
// LDS in phase 1) and writes undo only within that same segment.
__global__ __launch_bounds__(256) void sort_kernel(const int* __restrict__ buck,
                                                   int* __restrict__ sorted,
                                                   int* __restrict__ undo) {
  const int bh = blockIdx.x >> 1;
  const int half = blockIdx.x & 1;
  const int* bk = buck + (size_t)bh * NSORT + half * SS;
  int* out = sorted + (size_t)bh * NSORT + half * SS;
  int* und = undo + (size_t)bh * NSORT;
  __shared__ int cnt[64][128];
  __shared__ int bl[SS];
  __shared__ int bbase[128];
  __shared__ int total[128];
  const int tid = threadIdx.x;
  for (int i = tid; i < 64 * 128; i += 256) (&cnt[0][0])[i] = 0;
  __syncthreads();
#pragma unroll
  for (int j = 0; j < 16; ++j) {
    int i = j * 256 + tid;
    int e = bk[i];
    bl[i] = e;
    atomicAdd(&cnt[i >> 6][e & 127], 1);
  }
  __syncthreads();
  if (tid < 128) {
    int s = 0;
#pragma unroll 4
    for (int c = 0; c < 64; ++c) {
      int t = cnt[c][tid];
      cnt[c][tid] = s;
      s += t;
    }
    total[tid] = s;
  }
  __syncthreads();
  if (tid == 0) {
    int s = 0;
#pragma unroll 4
    for (int v = 0; v < 128; ++v) { bbase[v] = s; s += total[v]; }
  }
  __syncthreads();
  if (tid < 64) {
    const int i0 = tid << 6;
    const int orig0 = half * SS + i0;
#pragma unroll 4
    for (int j = 0; j < 64; ++j) {
      int v = bl[i0 + j] & 127;
      int off = cnt[tid][v];
      cnt[tid][v] = off + 1;
      int pos = bbase[v] + off;
      out[pos] = orig0 + j;
      und[orig0 + j] = half * SS + pos;   // undo[srt[j]] = j
    }
  }
}

// ---------------- MFMA chunked attention (smooth path, bf16) ----------------
__global__ __launch_bounds__(256) void attn_mfma_kernel(
    const unsigned short* __restrict__ qb16, const unsigned short* __restrict__ kb16,
    const unsigned short* __restrict__ vb16,
    const int* __restrict__ sq, const int* __restrict__ sk,
    float* __restrict__ outr, float* __restrict__ lr) {
  const int c = blockIdx.x, bh = blockIdx.y;
  const int cprev = (c + NCHUNKS - 1) & (NCHUNKS - 1);
  __shared__ unsigned short Qs[64][80];
  __shared__ unsigned short Ks[128][80];
  __shared__ unsigned short Vt[64][136];
  __shared__ unsigned short Ps[64][136];
  __shared__ int qpos[64];
  __shared__ int kvpos[128];
  __shared__ int krow[128];
  __shared__ float kscale[128];
  const int tid = threadIdx.x;
  const int* sqb = sq + (size_t)bh * NSORT;
  const int* skb = sk + (size_t)bh * NSORT;
  if (tid < 64) {
    int sqc = sqb[c * 64 + tid];
    int sqp = sqb[cprev * 64 + tid];
    qpos[tid] = sqc & (SS - 1);
    kvpos[tid] = sqp & (SS - 1);
    kvpos[64 + tid] = sqc & (SS - 1);
    krow[tid] = skb[cprev * 64 + tid] & (SS - 1);
    krow[64 + tid] = skb[c * 64 + tid] & (SS - 1);
  }
  __syncthreads();
  const unsigned short* kbase = kb16 + (size_t)bh * SS * DD;
  const unsigned short* vbase = vb16 + (size_t)bh * SS * DD;
  const unsigned short* qbase = qb16 + (size_t)bh * SS * DD;
#pragma unroll
  for (int it = 0; it < 4; ++it) {
    int id = tid + it * 256;
    int row = id >> 3, seg = id & 7;
    *(bf16x8*)&Ks[row][seg * 8] = *(const bf16x8*)(kbase + (size_t)krow[row] * DD + seg * 8);
  }
#pragma unroll
  for (int it = 0; it < 2; ++it) {
    int id = tid + it * 256;
    int row = id >> 3, seg = id & 7;
    *(bf16x8*)&Qs[row][seg * 8] = *(const bf16x8*)(qbase + (size_t)qpos[row] * DD + seg * 8);
  }
#pragma unroll
  for (int it = 0; it < 4; ++it) {
    int id = tid + it * 256;
    int col = id & 127, dg = id >> 7;
    bf16x8 v = *(const bf16x8*)(vbase + (size_t)krow[col] * DD + dg * 8);
#pragma unroll
    for (int i = 0; i < 8; ++i) Vt[dg * 8 + i][col] = (unsigned short)v[i];
  }
  __syncthreads();
  if (tid < 128) {
    float ss = 0.f;
#pragma unroll
    for (int seg = 0; seg < 8; ++seg) {
      bf16x8 t = *(const bf16x8*)&Ks[tid][seg * 8];
#pragma unroll
      for (int i = 0; i < 8; ++i) {
        float f = __uint_as_float(((unsigned)(unsigned short)t[i]) << 16);
        ss = fmaf(f, f, ss);
      }
    }
    kscale[tid] = rsqrtf(ss * (1.f / 64.f) + 1e-6f) * 0.125f;
  }
  __syncthreads();

  const int w = tid >> 6, l = tid & 63;
  const int lc = l & 15, lg = l >> 4;
  // ---- QK^T
  bf16x8 a0 = *(const bf16x8*)&Qs[w * 16 + lc][lg * 8];
  bf16x8 a1 = *(const bf16x8*)&Qs[w * 16 + lc][32 + lg * 8];
  f32x4 accs[8];
#pragma unroll
  for (int fi = 0; fi < 8; ++fi) {
    f32x4 acc = {0.f, 0.f, 0.f, 0.f};
    bf16x8 b0 = *(const bf16x8*)&Ks[fi * 16 + lc][lg * 8];
    bf16x8 b1 = *(const bf16x8*)&Ks[fi * 16 + lc][32 + lg * 8];
    acc = __builtin_amdgcn_mfma_f32_16x16x32_bf16(a0, b0, acc, 0, 0, 0);
    acc = __builtin_amdgcn_mfma_f32_16x16x32_bf16(a1, b1, acc, 0, 0, 0);
    accs[fi] = acc;
  }
  // ---- scale, self-mask, softmax
  float kcs[8]; int kvp[8];
#pragma unroll
  for (int fi = 0; fi < 8; ++fi) { kcs[fi] = kscale[fi * 16 + lc]; kvp[fi] = kvpos[fi * 16 + lc]; }
  float ex[8][4], logit_r[4], seinv_r[4];
#pragma unroll
  for (int r = 0; r < 4; ++r) {
    const int qp = qpos[w * 16 + lg * 4 + r];
    float mr = -3.402823466e38f;
#pragma unroll
    for (int fi = 0; fi < 8; ++fi) {
      float d = accs[fi][r] * kcs[fi];
      if (qp == kvp[fi]) d = -1e5f;
      ex[fi][r] = d;
      mr = fmaxf(mr, d);
    }
    mr = fmaxf(mr, __shfl_xor(mr, 1));
    mr = fmaxf(mr, __shfl_xor(mr, 2));
    mr = fmaxf(mr, __shfl_xor(mr, 4));
    mr = fmaxf(mr, __shfl_xor(mr, 8));
    float s = 0.f;
#pragma unroll
    for (int fi = 0; fi < 8; ++fi) { float e = expf(ex[fi][r] - mr); ex[fi][r] = e; s += e; }
    s += __shfl_xor(s, 1);
    s += __shfl_xor(s, 2);
    s += __shfl_xor(s, 4);
    s += __shfl_xor(s, 8);
    logit_r[r] = mr + logf(s);
    seinv_r[r] = 1.f / s;
  }
#pragma unroll
  for (int r = 0; r < 4; ++r) {
    int row = w * 16 + lg * 4 + r;
#pragma unroll
    for (int fi = 0; fi < 8; ++fi)
      Ps[row][fi * 16 + lc] = f2bf(ex[fi][r]);
    if (lc == 0) lr[(size_t)bh * NSORT + c * 64 + row] = logit_r[r];
  }
  __syncthreads();
  // ---- PV
  f32x4 acco[4];
#pragma unroll
  for (int fi2 = 0; fi2 < 4; ++fi2) acco[fi2] = {0.f, 0.f, 0.f, 0.f};
#pragma unroll
  for (int kg = 0; kg < 4; ++kg) {
    bf16x8 a = *(const bf16x8*)&Ps[w * 16 + lc][kg * 32 + lg * 8];
#pragma unroll
    for (int fi2 = 0; fi2 < 4; ++fi2) {
      bf16x8 b = *(const bf16x8*)&Vt[fi2 * 16 + lc][kg * 32 + lg * 8];
      acco[fi2] = __builtin_amdgcn_mfma_f32_16x16x32_bf16(a, b, acco[fi2], 0, 0, 0);
    }
  }
#pragma unroll
  for (int fi2 = 0; fi2 < 4; ++fi2) {
    int d = fi2 * 16 + lc;
#pragma unroll
    for (int r = 0; r < 4; ++r) {
      int row = w * 16 + lg * 4 + r;
      outr[((size_t)bh * NSORT + c * 64 + row) * DD + d] = acco[fi2][r] * seinv_r[r];
    }
  }
}

// ---------------- merge: undo-gather + round-logsumexp + transpose ------
__global__ void merge_kernel(const float* __restrict__ outr, const float* __restrict__ lr,
                             const int* __restrict__ undo, float* __restrict__ out) {
  const int idx = blockIdx.x * 256 + threadIdx.x;   // over B*H*S*16
  const int d4 = idx & 15;
  const int s = (idx >> 4) & (SS - 1);
  const int bh = idx >> 16;
  const int b = bh >> 4, h = bh & 15;
  const int u0 = undo[(size_t)bh * NSORT + s];
  const int u1 = undo[(size_t)bh * NSORT + SS + s];
  const float l0 = lr[(size_t)bh * NSORT + u0];
  const float l1 = lr[(size_t)bh * NSORT + u1];
  const float m = fmaxf(l0, l1);
  float w0 = expf(l0 - m), w1 = expf(l1 - m);
  const float inv = 1.f / (w0 + w1);
  w0 *= inv; w1 *= inv;
  const float4 r0 = *(const float4*)(outr + ((size_t)bh * NSORT + u0) * DD + d4 * 4);
  const float4 r1 = *(const float4*)(outr + ((size_t)bh * NSORT + u1) * DD + d4 * 4);
  float4 o;
  o.x = w0 * r0.x + w1 * r1.x;
  o.y = w0 * r0.y + w1 * r1.y;
  o.z = w0 * r0.z + w1 * r1.z;
  o.w = w0 * r0.w + w1 * r1.w;
  *(float4*)(out + ((size_t)(b * SS + s) * 1024) + h * 64 + d4 * 4) = o;
}

extern "C" void kernel_launch(void* const* d_in, const int* in_sizes, int n_in,
                              void* d_out, int out_size, void* d_ws, size_t ws_size,
                              hipStream_t stream) {
  if (ws_size < WS_REQUIRED) return;
  const float* dec = (const float*)d_in[0];
  const float* hid = (const float*)d_in[1];
  const float* wqk = (const float*)d_in[2];
  const float* wv  = (const float*)d_in[3];
  float* out = (float*)d_out;
  char* ws = (char*)d_ws;
  float* q    = (float*)(ws + OFF_Q);
  float* kk   = (float*)(ws + OFF_K);
  unsigned short* vbf = (unsigned short*)(ws + OFF_V);
  float* rotp = (float*)(ws + OFF_ROT);
  int*   qb   = (int*)(ws + OFF_QB);    // q-buckets
  int*   kbk  = (int*)(ws + OFF_KB);    // k-buckets, becomes undo_k in k-sort
  int*   sqi  = (int*)(ws + OFF_SQ);
  int*   ski  = (int*)(ws + OFF_SK);
  float* outr = (float*)(ws + OFF_OUTR);
  float* lrp  = (float*)(ws + OFF_LR);
  unsigned short* qbf = (unsigned short*)(ws + OFF_QBF);
  unsigned short* kbf = (unsigned short*)(ws + OFF_KBF);

  gen_rot_kernel<<<512, 256, 0, stream>>>(rotp);
  gemm_kernel<<<dim3(64, 16), 256, 0, stream>>>(dec, wqk, q, qbf);
  gemm_kernel<<<dim3(64, 16), 256, 0, stream>>>(hid, wqk, kk, kbf);
  gemm_v_mfma<<<dim3(128, 16), 256, 0, stream>>>(hid, wv, vbf);
  hash_kernel<<<dim3(32, 32), 128, 0, stream>>>(q, rotp, qb);
  hash_kernel<<<dim3(32, 32), 128, 0, stream>>>(kk, rotp, kbk);
  sort_kernel<<<64, 256, 0, stream>>>(qb, sqi, qb);    // q-undo unused (in-place, safe)
  sort_kernel<<<64, 256, 0, stream>>>(kbk, ski, kbk);  // kbk becomes undo_k
  attn_mfma_kernel<<<dim3(128, 32), 256, 0, stream>>>(qbf, kbf, vbf, sqi, ski, outr, lrp);
  merge_kernel<<<8192, 256, 0, stream>>>(outr, lrp, kbk, out);
}